// Round 2
// baseline (1233.699 us; speedup 1.0000x reference)
//
#include <hip/hip_runtime.h>
#include <math.h>

#define NN 100000
#define NE 800000
#define F 128
#define KK 256
#define OUTD 40
#define EPSF 1e-5f
#define NB 391  // ceil(NN/256)

// ---------------- edge_index dtype normalization ----------------
// Reference declares int64; harness docs say int32. Detect on device:
// if the data is int64 (values < 2^31), every odd 32-bit word is 0.
__global__ void detect_kernel(const int* __restrict__ ei_raw, int* __restrict__ flag) {
  __shared__ int any;
  if (threadIdx.x == 0) any = 0;
  __syncthreads();
  if (ei_raw[2 * threadIdx.x + 1] != 0) atomicOr(&any, 1);
  __syncthreads();
  if (threadIdx.x == 0) *flag = (any == 0) ? 1 : 0;  // 1 => int64 source
}

__global__ __launch_bounds__(256) void conv_kernel(const int* __restrict__ ei_raw,
                                                   const int* __restrict__ flag,
                                                   int* __restrict__ es) {
  int i = blockIdx.x * 256 + threadIdx.x;
  if (i < 2 * NE) {
    int f = *flag;
    es[i] = f ? ei_raw[2 * i] : ei_raw[i];
  }
}

// ---------------- CSR build (dst-keyed, stores src) ----------------
__global__ __launch_bounds__(256) void deg_kernel(const int* __restrict__ dst,
                                                  int* __restrict__ deg) {
  int e = blockIdx.x * 256 + threadIdx.x;
  if (e < NE) atomicAdd(&deg[dst[e]], 1);
}

__global__ __launch_bounds__(256) void scan1(const int* __restrict__ deg,
                                             int* __restrict__ offs,
                                             int* __restrict__ bsum) {
  __shared__ int sh[256];
  const int tid = threadIdx.x;
  const int i = blockIdx.x * 256 + tid;
  int v = (i < NN) ? deg[i] : 0;
  sh[tid] = v;
  __syncthreads();
#pragma unroll
  for (int off = 1; off < 256; off <<= 1) {
    int add = (tid >= off) ? sh[tid - off] : 0;
    __syncthreads();
    sh[tid] += add;
    __syncthreads();
  }
  if (i < NN) offs[i] = sh[tid] - v;  // exclusive
  if (tid == 255) bsum[blockIdx.x] = sh[255];
}

__global__ void scan2(int* __restrict__ bsum) {
  __shared__ int sh[512];
  const int t = threadIdx.x;
  int v = (t < NB) ? bsum[t] : 0;
  sh[t] = v;
  __syncthreads();
#pragma unroll
  for (int off = 1; off < 512; off <<= 1) {
    int add = (t >= off) ? sh[t - off] : 0;
    __syncthreads();
    sh[t] += add;
    __syncthreads();
  }
  if (t < NB) bsum[t] = sh[t] - v;  // exclusive block offsets
}

__global__ __launch_bounds__(256) void scan3(int* __restrict__ offs,
                                             int* __restrict__ woff,
                                             const int* __restrict__ bsum) {
  int i = blockIdx.x * 256 + threadIdx.x;
  if (i < NN) {
    int o = offs[i] + bsum[blockIdx.x];
    offs[i] = o;
    woff[i] = o;
  }
  if (i == 0) offs[NN] = NE;
}

__global__ __launch_bounds__(256) void fill_kernel(const int* __restrict__ src,
                                                   const int* __restrict__ dst,
                                                   int* __restrict__ woff,
                                                   int* __restrict__ eidx) {
  int e = blockIdx.x * 256 + threadIdx.x;
  if (e < NE) {
    int pos = atomicAdd(&woff[dst[e]], 1);
    eidx[pos] = src[e];
  }
}

// ---------------- gather-based mean aggregation ----------------
// 32 lanes per node row; each lane owns one float4 column slice.
__global__ __launch_bounds__(256) void gather_kernel(const float* __restrict__ xin,
                                                     const int* __restrict__ eidx,
                                                     const int* __restrict__ offs,
                                                     float* __restrict__ agg) {
  int tid = blockIdx.x * 256 + threadIdx.x;
  int n = tid >> 5;
  int q = tid & 31;
  int beg = offs[n];
  int end = offs[n + 1];
  float ax = 0.f, ay = 0.f, az = 0.f, aw = 0.f;
  for (int i = beg; i < end; ++i) {
    int s = eidx[i];
    float4 v = *(const float4*)(xin + (size_t)s * F + q * 4);
    ax += v.x; ay += v.y; az += v.z; aw += v.w;
  }
  float scl = 1.0f / fmaxf((float)(end - beg), 1.0f);
  float4 o;
  o.x = ax * scl; o.y = ay * scl; o.z = az * scl; o.w = aw * scl;
  *(float4*)(agg + (size_t)n * F + q * 4) = o;
}

// ---------------- fused dual GEMM: out = agg@Wl + bl + x@Wr ----------------
__global__ __launch_bounds__(256) void gemm_fused(const float* __restrict__ agg,
                                                  const float* __restrict__ xin,
                                                  const float* __restrict__ Wl,
                                                  const float* __restrict__ bl,
                                                  const float* __restrict__ Wr,
                                                  float* __restrict__ out) {
  __shared__ float tile[32][KK];
  const int t = threadIdx.x;
  const int row0 = blockIdx.x * 32;
#pragma unroll
  for (int i = 0; i < 8; ++i) {
    int slot = t + i * 256;      // 0..2047
    int r = slot >> 6;           // tile row
    int c4 = slot & 63;          // float4 column
    int row = row0 + r;
    float4 v;
    if (c4 < 32) {
      v = *(const float4*)(agg + (size_t)row * F + c4 * 4);
    } else {
      v = *(const float4*)(xin + (size_t)row * F + (c4 - 32) * 4);
    }
    *(float4*)(&tile[r][c4 * 4]) = v;
  }
  __syncthreads();

  const int tx = t & 31;   // column group (4 cols)
  const int ty = t >> 5;   // row group (4 rows)
  float acc[4][4];
#pragma unroll
  for (int r = 0; r < 4; ++r)
#pragma unroll
    for (int c = 0; c < 4; ++c) acc[r][c] = 0.f;

#pragma unroll 1
  for (int half = 0; half < 2; ++half) {
    const float* __restrict__ Wp = half ? Wr : Wl;
    const int kb = half * 128;
    for (int k = 0; k < 128; k += 4) {
      float4 in4[4];
#pragma unroll
      for (int r = 0; r < 4; ++r)
        in4[r] = *(const float4*)(&tile[ty * 4 + r][kb + k]);
#pragma unroll
      for (int i = 0; i < 4; ++i) {
        float4 w = *(const float4*)(Wp + (size_t)(k + i) * F + tx * 4);
        float a[4];
        a[0] = ((const float*)&in4[0])[i];
        a[1] = ((const float*)&in4[1])[i];
        a[2] = ((const float*)&in4[2])[i];
        a[3] = ((const float*)&in4[3])[i];
#pragma unroll
        for (int r = 0; r < 4; ++r) {
          acc[r][0] = fmaf(a[r], w.x, acc[r][0]);
          acc[r][1] = fmaf(a[r], w.y, acc[r][1]);
          acc[r][2] = fmaf(a[r], w.z, acc[r][2]);
          acc[r][3] = fmaf(a[r], w.w, acc[r][3]);
        }
      }
    }
  }
  float4 b4 = *(const float4*)(bl + tx * 4);
#pragma unroll
  for (int r = 0; r < 4; ++r) {
    float4 o;
    o.x = acc[r][0] + b4.x;
    o.y = acc[r][1] + b4.y;
    o.z = acc[r][2] + b4.z;
    o.w = acc[r][3] + b4.w;
    *(float4*)(out + (size_t)(row0 + ty * 4 + r) * F + tx * 4) = o;
  }
}

// ---------------- BatchNorm statistics ----------------
__global__ __launch_bounds__(256) void bn_stats(const float* __restrict__ h,
                                                float* __restrict__ sums) {
  __shared__ float red[256];
  const int c = threadIdx.x & 127;
  const int rg = threadIdx.x >> 7;  // 0 or 1
  float s = 0.f, s2 = 0.f;
  for (int row = blockIdx.x * 2 + rg; row < NN; row += gridDim.x * 2) {
    float v = h[(size_t)row * F + c];
    s += v;
    s2 = fmaf(v, v, s2);
  }
  red[threadIdx.x] = s;
  __syncthreads();
  if (rg == 0) atomicAdd(&sums[c], s + red[128 + c]);
  __syncthreads();
  red[threadIdx.x] = s2;
  __syncthreads();
  if (rg == 0) atomicAdd(&sums[128 + c], s2 + red[128 + c]);
}

__global__ void bn_params(const float* __restrict__ sums, const float* __restrict__ g,
                          const float* __restrict__ b, float* __restrict__ sc) {
  int c = threadIdx.x;  // 128
  float mu = sums[c] * (1.0f / NN);
  float var = sums[128 + c] * (1.0f / NN) - mu * mu;
  float scale = g[c] * rsqrtf(var + EPSF);
  sc[c] = scale;
  sc[128 + c] = b[c] - mu * scale;
}

// ---------------- BN apply + ReLU (in place) ----------------
__global__ __launch_bounds__(256) void bn_apply(float* __restrict__ h,
                                                const float* __restrict__ sc) {
  int tid = blockIdx.x * 256 + threadIdx.x;  // NN*32 threads, one float4 each
  int c4 = tid & 31;
  float4 v = *(float4*)(h + (size_t)tid * 4);
  float4 scale = *(const float4*)(sc + c4 * 4);
  float4 shift = *(const float4*)(sc + 128 + c4 * 4);
  v.x = fmaxf(fmaf(v.x, scale.x, shift.x), 0.f);
  v.y = fmaxf(fmaf(v.y, scale.y, shift.y), 0.f);
  v.z = fmaxf(fmaf(v.z, scale.z, shift.z), 0.f);
  v.w = fmaxf(fmaf(v.w, scale.w, shift.w), 0.f);
  *(float4*)(h + (size_t)tid * 4) = v;
}

// ---------------- final layer (K=256 -> 40 cols) + log_softmax ----------------
__device__ __forceinline__ float bcastf(float v, int lane) {
  return __int_as_float(__builtin_amdgcn_readlane(__float_as_int(v), lane));
}

__global__ __launch_bounds__(256) void final_kernel(const float* __restrict__ agg,
                                                    const float* __restrict__ h,
                                                    const float* __restrict__ Wl,
                                                    const float* __restrict__ bl,
                                                    const float* __restrict__ Wr,
                                                    float* __restrict__ out) {
  const int lane = threadIdx.x & 63;
  const int row = blockIdx.x * 4 + (threadIdx.x >> 6);
  if (row >= NN) return;  // wave-uniform
  float4 v;
  if (lane < 32) {
    v = *(const float4*)(agg + (size_t)row * F + lane * 4);
  } else {
    v = *(const float4*)(h + (size_t)row * F + (lane - 32) * 4);
  }
  const int j = (lane < OUTD) ? lane : 0;
  float acc = 0.f;
#pragma unroll
  for (int sl = 0; sl < 64; ++sl) {
    float a0 = bcastf(v.x, sl);
    float a1 = bcastf(v.y, sl);
    float a2 = bcastf(v.z, sl);
    float a3 = bcastf(v.w, sl);
    const int k = sl * 4;
    const float* __restrict__ Wp =
        (k < 128) ? (Wl + (size_t)k * OUTD) : (Wr + (size_t)(k - 128) * OUTD);
    acc = fmaf(a0, Wp[0 * OUTD + j], acc);
    acc = fmaf(a1, Wp[1 * OUTD + j], acc);
    acc = fmaf(a2, Wp[2 * OUTD + j], acc);
    acc = fmaf(a3, Wp[3 * OUTD + j], acc);
  }
  acc += bl[j];
  float m = (lane < OUTD) ? acc : -INFINITY;
#pragma unroll
  for (int off = 32; off > 0; off >>= 1) m = fmaxf(m, __shfl_xor(m, off));
  float ex = (lane < OUTD) ? expf(acc - m) : 0.f;
  float ssum = ex;
#pragma unroll
  for (int off = 32; off > 0; off >>= 1) ssum += __shfl_xor(ssum, off);
  if (lane < OUTD) out[(size_t)row * OUTD + lane] = acc - m - logf(ssum);
}

// ---------------- driver ----------------
extern "C" void kernel_launch(void* const* d_in, const int* in_sizes, int n_in,
                              void* d_out, int out_size, void* d_ws, size_t ws_size,
                              hipStream_t stream) {
  const float* x = (const float*)d_in[0];
  const int* ei_raw = (const int*)d_in[1];
  const float* Wl[4] = {(const float*)d_in[2], (const float*)d_in[5],
                        (const float*)d_in[8], (const float*)d_in[11]};
  const float* bl[4] = {(const float*)d_in[3], (const float*)d_in[6],
                        (const float*)d_in[9], (const float*)d_in[12]};
  const float* Wr[4] = {(const float*)d_in[4], (const float*)d_in[7],
                        (const float*)d_in[10], (const float*)d_in[13]};
  const float* g[3] = {(const float*)d_in[14], (const float*)d_in[16],
                       (const float*)d_in[18]};
  const float* bb[3] = {(const float*)d_in[15], (const float*)d_in[17],
                        (const float*)d_in[19]};

  char* wsb = (char*)d_ws;
  float* agg = (float*)wsb;                       wsb += (size_t)NN * F * 4;
  float* hA  = (float*)wsb;                       wsb += (size_t)NN * F * 4;
  float* hB  = (float*)wsb;                       wsb += (size_t)NN * F * 4;
  int* es    = (int*)wsb;                         wsb += (size_t)2 * NE * 4;
  int* eidx  = (int*)wsb;                         wsb += (size_t)NE * 4;
  int* offs  = (int*)wsb;                         wsb += (size_t)(NN + 64) * 4;
  int* woff  = (int*)wsb;                         wsb += (size_t)(NN + 64) * 4;
  int* bsum  = (int*)wsb;                         wsb += 512 * 4;
  float* sums = (float*)wsb;                      wsb += 256 * 4;
  float* sc   = (float*)wsb;                      wsb += 256 * 4;
  int* flag   = (int*)wsb;                        wsb += 256;

  int* esrc = es;
  int* edst = es + NE;

  // --- edge_index normalization (int64 vs int32) ---
  detect_kernel<<<1, 256, 0, stream>>>(ei_raw, flag);
  conv_kernel<<<(2 * NE + 255) / 256, 256, 0, stream>>>(ei_raw, flag, es);

  // --- CSR build (dst-keyed) ---
  hipMemsetAsync(woff, 0, NN * sizeof(int), stream);
  deg_kernel<<<NE / 256, 256, 0, stream>>>(edst, woff);
  scan1<<<NB, 256, 0, stream>>>(woff, offs, bsum);
  scan2<<<1, 512, 0, stream>>>(bsum);
  scan3<<<NB, 256, 0, stream>>>(offs, woff, bsum);
  fill_kernel<<<NE / 256, 256, 0, stream>>>(esrc, edst, woff, eidx);

  const float* cur = x;
  float* bufs[2] = {hA, hB};
  for (int L = 0; L < 3; ++L) {
    float* hpre = bufs[L & 1];
    gather_kernel<<<NN * 32 / 256, 256, 0, stream>>>(cur, eidx, offs, agg);
    gemm_fused<<<NN / 32, 256, 0, stream>>>(agg, cur, Wl[L], bl[L], Wr[L], hpre);
    hipMemsetAsync(sums, 0, 256 * sizeof(float), stream);
    bn_stats<<<1024, 256, 0, stream>>>(hpre, sums);
    bn_params<<<1, 128, 0, stream>>>(sums, g[L], bb[L], sc);
    bn_apply<<<NN * 32 / 256, 256, 0, stream>>>(hpre, sc);
    cur = hpre;
  }
  // layer 4 + log_softmax
  gather_kernel<<<NN * 32 / 256, 256, 0, stream>>>(cur, eidx, offs, agg);
  final_kernel<<<NN / 4, 256, 0, stream>>>(agg, cur, Wl[3], bl[3], Wr[3],
                                           (float*)d_out);
}

// Round 3
// 1052.188 us; speedup vs baseline: 1.1725x; 1.1725x over previous
//
#include <hip/hip_runtime.h>
#include <math.h>

#define NN 100000
#define NE 800000
#define F 128
#define KK 256
#define OUTD 40
#define EPSF 1e-5f
#define NB 391   // ceil(NN/256)
#define FROWS 16 // rows per block in final kernel

// ---------------- edge_index dtype normalization ----------------
__global__ void detect_kernel(const int* __restrict__ ei_raw, int* __restrict__ flag) {
  __shared__ int any;
  if (threadIdx.x == 0) any = 0;
  __syncthreads();
  if (ei_raw[2 * threadIdx.x + 1] != 0) atomicOr(&any, 1);
  __syncthreads();
  if (threadIdx.x == 0) *flag = (any == 0) ? 1 : 0;  // 1 => int64 source
}

__global__ __launch_bounds__(256) void conv_kernel(const int* __restrict__ ei_raw,
                                                   const int* __restrict__ flag,
                                                   int* __restrict__ es) {
  int i = blockIdx.x * 256 + threadIdx.x;
  if (i < 2 * NE) {
    int f = *flag;
    es[i] = f ? ei_raw[2 * i] : ei_raw[i];
  }
}

// ---------------- CSR build (dst-keyed, stores src) ----------------
__global__ __launch_bounds__(256) void deg_kernel(const int* __restrict__ dst,
                                                  int* __restrict__ deg) {
  int e = blockIdx.x * 256 + threadIdx.x;
  if (e < NE) atomicAdd(&deg[dst[e]], 1);
}

__global__ __launch_bounds__(256) void scan1(const int* __restrict__ deg,
                                             int* __restrict__ offs,
                                             int* __restrict__ bsum) {
  __shared__ int sh[256];
  const int tid = threadIdx.x;
  const int i = blockIdx.x * 256 + tid;
  int v = (i < NN) ? deg[i] : 0;
  sh[tid] = v;
  __syncthreads();
#pragma unroll
  for (int off = 1; off < 256; off <<= 1) {
    int add = (tid >= off) ? sh[tid - off] : 0;
    __syncthreads();
    sh[tid] += add;
    __syncthreads();
  }
  if (i < NN) offs[i] = sh[tid] - v;  // exclusive
  if (tid == 255) bsum[blockIdx.x] = sh[255];
}

__global__ void scan2(int* __restrict__ bsum) {
  __shared__ int sh[512];
  const int t = threadIdx.x;
  int v = (t < NB) ? bsum[t] : 0;
  sh[t] = v;
  __syncthreads();
#pragma unroll
  for (int off = 1; off < 512; off <<= 1) {
    int add = (t >= off) ? sh[t - off] : 0;
    __syncthreads();
    sh[t] += add;
    __syncthreads();
  }
  if (t < NB) bsum[t] = sh[t] - v;  // exclusive block offsets
}

__global__ __launch_bounds__(256) void scan3(int* __restrict__ offs,
                                             int* __restrict__ woff,
                                             const int* __restrict__ bsum) {
  int i = blockIdx.x * 256 + threadIdx.x;
  if (i < NN) {
    int o = offs[i] + bsum[blockIdx.x];
    offs[i] = o;
    woff[i] = o;
  }
  if (i == 0) offs[NN] = NE;
}

__global__ __launch_bounds__(256) void fill_kernel(const int* __restrict__ src,
                                                   const int* __restrict__ dst,
                                                   int* __restrict__ woff,
                                                   int* __restrict__ eidx) {
  int e = blockIdx.x * 256 + threadIdx.x;
  if (e < NE) {
    int pos = atomicAdd(&woff[dst[e]], 1);
    eidx[pos] = src[e];
  }
}

// ---------------- gather-based mean aggregation (+ fused BN/ReLU of source) ----
// 32 lanes per node row; each lane owns one float4 column slice. 4-edge unroll
// puts 4 independent 16B gathers in flight per lane.
template <int BN>
__global__ __launch_bounds__(256) void gather_kernel(const float* __restrict__ xin,
                                                     const int* __restrict__ eidx,
                                                     const int* __restrict__ offs,
                                                     const float* __restrict__ sc,
                                                     float* __restrict__ agg) {
  int tid = blockIdx.x * 256 + threadIdx.x;
  int n = tid >> 5;
  int q = tid & 31;
  int beg = offs[n];
  int end = offs[n + 1];
  float4 scl, shf;
  if (BN) {
    scl = *(const float4*)(sc + q * 4);
    shf = *(const float4*)(sc + 128 + q * 4);
  }
  float ax = 0.f, ay = 0.f, az = 0.f, aw = 0.f;
#define ACCV(vv)                                         \
  do {                                                   \
    if (BN) {                                            \
      vv.x = fmaxf(fmaf(vv.x, scl.x, shf.x), 0.f);       \
      vv.y = fmaxf(fmaf(vv.y, scl.y, shf.y), 0.f);       \
      vv.z = fmaxf(fmaf(vv.z, scl.z, shf.z), 0.f);       \
      vv.w = fmaxf(fmaf(vv.w, scl.w, shf.w), 0.f);       \
    }                                                    \
    ax += vv.x; ay += vv.y; az += vv.z; aw += vv.w;      \
  } while (0)
  int i = beg;
  for (; i + 4 <= end; i += 4) {
    int s0 = eidx[i], s1 = eidx[i + 1], s2 = eidx[i + 2], s3 = eidx[i + 3];
    float4 v0 = *(const float4*)(xin + (size_t)s0 * F + q * 4);
    float4 v1 = *(const float4*)(xin + (size_t)s1 * F + q * 4);
    float4 v2 = *(const float4*)(xin + (size_t)s2 * F + q * 4);
    float4 v3 = *(const float4*)(xin + (size_t)s3 * F + q * 4);
    ACCV(v0); ACCV(v1); ACCV(v2); ACCV(v3);
  }
  for (; i < end; ++i) {
    int s0 = eidx[i];
    float4 v0 = *(const float4*)(xin + (size_t)s0 * F + q * 4);
    ACCV(v0);
  }
#undef ACCV
  float m = 1.0f / fmaxf((float)(end - beg), 1.0f);
  float4 o;
  o.x = ax * m; o.y = ay * m; o.z = az * m; o.w = aw * m;
  *(float4*)(agg + (size_t)n * F + q * 4) = o;
}

// ------ fused dual GEMM: out = agg@Wl + bl + bnrelu(x)@Wr, + BN-stats epilogue ----
template <int BN>
__global__ __launch_bounds__(256) void gemm_fused(const float* __restrict__ agg,
                                                  const float* __restrict__ xin,
                                                  const float* __restrict__ sc,
                                                  const float* __restrict__ Wl,
                                                  const float* __restrict__ bl,
                                                  const float* __restrict__ Wr,
                                                  float* __restrict__ out,
                                                  float* __restrict__ sums) {
  __shared__ float tile[32][KK];  // 32 KB
  const int t = threadIdx.x;
  const int row0 = blockIdx.x * 32;
#pragma unroll
  for (int i = 0; i < 8; ++i) {
    int slot = t + i * 256;      // 0..2047
    int r = slot >> 6;           // tile row
    int c4 = slot & 63;          // float4 column
    int row = row0 + r;
    float4 v;
    if (c4 < 32) {
      v = *(const float4*)(agg + (size_t)row * F + c4 * 4);  // already BN'd/mean'd
    } else {
      int c = (c4 - 32) * 4;
      v = *(const float4*)(xin + (size_t)row * F + c);
      if (BN) {
        float4 s4 = *(const float4*)(sc + c);
        float4 b4 = *(const float4*)(sc + 128 + c);
        v.x = fmaxf(fmaf(v.x, s4.x, b4.x), 0.f);
        v.y = fmaxf(fmaf(v.y, s4.y, b4.y), 0.f);
        v.z = fmaxf(fmaf(v.z, s4.z, b4.z), 0.f);
        v.w = fmaxf(fmaf(v.w, s4.w, b4.w), 0.f);
      }
    }
    *(float4*)(&tile[r][c4 * 4]) = v;
  }
  __syncthreads();

  const int tx = t & 31;   // column group (4 cols)
  const int ty = t >> 5;   // row group (4 rows)
  float acc[4][4];
#pragma unroll
  for (int r = 0; r < 4; ++r)
#pragma unroll
    for (int c = 0; c < 4; ++c) acc[r][c] = 0.f;

#pragma unroll 1
  for (int half = 0; half < 2; ++half) {
    const float* __restrict__ Wp = half ? Wr : Wl;
    const int kb = half * 128;
    for (int k = 0; k < 128; k += 4) {
      float4 in4[4];
#pragma unroll
      for (int r = 0; r < 4; ++r)
        in4[r] = *(const float4*)(&tile[ty * 4 + r][kb + k]);
#pragma unroll
      for (int i = 0; i < 4; ++i) {
        float4 w = *(const float4*)(Wp + (size_t)(k + i) * F + tx * 4);
        float a[4];
        a[0] = ((const float*)&in4[0])[i];
        a[1] = ((const float*)&in4[1])[i];
        a[2] = ((const float*)&in4[2])[i];
        a[3] = ((const float*)&in4[3])[i];
#pragma unroll
        for (int r = 0; r < 4; ++r) {
          acc[r][0] = fmaf(a[r], w.x, acc[r][0]);
          acc[r][1] = fmaf(a[r], w.y, acc[r][1]);
          acc[r][2] = fmaf(a[r], w.z, acc[r][2]);
          acc[r][3] = fmaf(a[r], w.w, acc[r][3]);
        }
      }
    }
  }
  float4 b4 = *(const float4*)(bl + tx * 4);
  float ps[4] = {0.f, 0.f, 0.f, 0.f};
  float pq[4] = {0.f, 0.f, 0.f, 0.f};
#pragma unroll
  for (int r = 0; r < 4; ++r) {
    float4 o;
    o.x = acc[r][0] + b4.x;
    o.y = acc[r][1] + b4.y;
    o.z = acc[r][2] + b4.z;
    o.w = acc[r][3] + b4.w;
    ps[0] += o.x; pq[0] = fmaf(o.x, o.x, pq[0]);
    ps[1] += o.y; pq[1] = fmaf(o.y, o.y, pq[1]);
    ps[2] += o.z; pq[2] = fmaf(o.z, o.z, pq[2]);
    ps[3] += o.w; pq[3] = fmaf(o.w, o.w, pq[3]);
    *(float4*)(out + (size_t)(row0 + ty * 4 + r) * F + tx * 4) = o;
  }
  // BN-stats epilogue: per-column block partials -> LDS reduce -> atomics
  __syncthreads();
  float* red = &tile[0][0];  // reuse: [2][8][128] floats = 8 KB
#pragma unroll
  for (int j = 0; j < 4; ++j) {
    red[ty * 128 + tx * 4 + j] = ps[j];
    red[2048 + ty * 128 + tx * 4 + j] = pq[j];
  }
  __syncthreads();
  if (t < 128) {
    float s = 0.f, qq = 0.f;
#pragma unroll
    for (int g2 = 0; g2 < 8; ++g2) {
      s += red[g2 * 128 + t];
      qq += red[2048 + g2 * 128 + t];
    }
    atomicAdd(&sums[t], s);
    atomicAdd(&sums[128 + t], qq);
  }
}

// ---------------- BN parameter computation ----------------
__global__ void bn_params(const float* __restrict__ sums, const float* __restrict__ g,
                          const float* __restrict__ b, float* __restrict__ sc) {
  int c = threadIdx.x;  // 128
  float mu = sums[c] * (1.0f / NN);
  float var = sums[128 + c] * (1.0f / NN) - mu * mu;
  float scale = g[c] * rsqrtf(var + EPSF);
  sc[c] = scale;
  sc[128 + c] = b[c] - mu * scale;
}

// ------- final layer: LDS-tiled GEMM (K=256 -> 40) + fused log_softmax -------
__global__ __launch_bounds__(256) void final_kernel(const float* __restrict__ agg,
                                                    const float* __restrict__ h,
                                                    const float* __restrict__ sc,
                                                    const float* __restrict__ Wl,
                                                    const float* __restrict__ bl,
                                                    const float* __restrict__ Wr,
                                                    float* __restrict__ out) {
  __shared__ float tile[FROWS][KK];  // 16 KB
  __shared__ float wlds[KK][OUTD];   // 40 KB
  const int t = threadIdx.x;
  for (int i = t; i < KK * OUTD; i += 256) {
    int k = i / OUTD, j = i - k * OUTD;
    wlds[k][j] = (k < F) ? Wl[k * OUTD + j] : Wr[(k - F) * OUTD + j];
  }
  const int row0 = blockIdx.x * FROWS;
#pragma unroll
  for (int i = 0; i < 4; ++i) {
    int slot = t + i * 256;  // 0..1023
    int r = slot >> 6, c4 = slot & 63;
    int row = row0 + r;
    float4 v;
    if (c4 < 32) {
      v = *(const float4*)(agg + (size_t)row * F + c4 * 4);
    } else {
      int c = (c4 - 32) * 4;
      v = *(const float4*)(h + (size_t)row * F + c);
      float4 s4 = *(const float4*)(sc + c);
      float4 b4 = *(const float4*)(sc + 128 + c);
      v.x = fmaxf(fmaf(v.x, s4.x, b4.x), 0.f);
      v.y = fmaxf(fmaf(v.y, s4.y, b4.y), 0.f);
      v.z = fmaxf(fmaf(v.z, s4.z, b4.z), 0.f);
      v.w = fmaxf(fmaf(v.w, s4.w, b4.w), 0.f);
    }
    *(float4*)(&tile[r][c4 * 4]) = v;
  }
  __syncthreads();
  const int tx = t & 63;   // output column (40 active)
  const int wv = t >> 6;   // wave id: rows wv*4 .. wv*4+3
  const int jj = (tx < OUTD) ? tx : 0;
  float acc[4] = {0.f, 0.f, 0.f, 0.f};
  for (int k = 0; k < KK; k += 4) {
    float w0 = wlds[k][jj], w1 = wlds[k + 1][jj];
    float w2 = wlds[k + 2][jj], w3 = wlds[k + 3][jj];
#pragma unroll
    for (int r = 0; r < 4; ++r) {
      float4 a = *(const float4*)(&tile[wv * 4 + r][k]);  // wave-uniform broadcast
      acc[r] = fmaf(a.x, w0, acc[r]);
      acc[r] = fmaf(a.y, w1, acc[r]);
      acc[r] = fmaf(a.z, w2, acc[r]);
      acc[r] = fmaf(a.w, w3, acc[r]);
    }
  }
  float bias = bl[jj];
#pragma unroll
  for (int r = 0; r < 4; ++r) {
    float v = acc[r] + bias;
    float m = (tx < OUTD) ? v : -INFINITY;
#pragma unroll
    for (int off = 32; off > 0; off >>= 1) m = fmaxf(m, __shfl_xor(m, off));
    float e = (tx < OUTD) ? expf(v - m) : 0.f;
    float s = e;
#pragma unroll
    for (int off = 32; off > 0; off >>= 1) s += __shfl_xor(s, off);
    if (tx < OUTD) out[(size_t)(row0 + wv * 4 + r) * OUTD + tx] = v - m - logf(s);
  }
}

// ---------------- driver ----------------
extern "C" void kernel_launch(void* const* d_in, const int* in_sizes, int n_in,
                              void* d_out, int out_size, void* d_ws, size_t ws_size,
                              hipStream_t stream) {
  const float* x = (const float*)d_in[0];
  const int* ei_raw = (const int*)d_in[1];
  const float* Wl[4] = {(const float*)d_in[2], (const float*)d_in[5],
                        (const float*)d_in[8], (const float*)d_in[11]};
  const float* bl[4] = {(const float*)d_in[3], (const float*)d_in[6],
                        (const float*)d_in[9], (const float*)d_in[12]};
  const float* Wr[4] = {(const float*)d_in[4], (const float*)d_in[7],
                        (const float*)d_in[10], (const float*)d_in[13]};
  const float* g[3] = {(const float*)d_in[14], (const float*)d_in[16],
                       (const float*)d_in[18]};
  const float* bb[3] = {(const float*)d_in[15], (const float*)d_in[17],
                        (const float*)d_in[19]};

  char* wsb = (char*)d_ws;
  float* agg = (float*)wsb;                       wsb += (size_t)NN * F * 4;
  float* hA  = (float*)wsb;                       wsb += (size_t)NN * F * 4;
  float* hB  = (float*)wsb;                       wsb += (size_t)NN * F * 4;
  int* es    = (int*)wsb;                         wsb += (size_t)2 * NE * 4;
  int* eidx  = (int*)wsb;                         wsb += (size_t)NE * 4;
  int* offs  = (int*)wsb;                         wsb += (size_t)(NN + 64) * 4;
  int* woff  = (int*)wsb;                         wsb += (size_t)(NN + 64) * 4;
  int* bsum  = (int*)wsb;                         wsb += 512 * 4;
  float* sums = (float*)wsb;                      wsb += 256 * 4;
  float* sc   = (float*)wsb;                      wsb += 256 * 4;
  int* flag   = (int*)wsb;                        wsb += 256;

  int* esrc = es;
  int* edst = es + NE;

  // --- edge_index normalization (int64 vs int32) ---
  detect_kernel<<<1, 256, 0, stream>>>(ei_raw, flag);
  conv_kernel<<<(2 * NE + 255) / 256, 256, 0, stream>>>(ei_raw, flag, es);

  // --- CSR build (dst-keyed) ---
  hipMemsetAsync(woff, 0, NN * sizeof(int), stream);
  deg_kernel<<<NE / 256, 256, 0, stream>>>(edst, woff);
  scan1<<<NB, 256, 0, stream>>>(woff, offs, bsum);
  scan2<<<1, 512, 0, stream>>>(bsum);
  scan3<<<NB, 256, 0, stream>>>(offs, woff, bsum);
  fill_kernel<<<NE / 256, 256, 0, stream>>>(esrc, edst, woff, eidx);

  const float* cur = x;
  float* bufs[2] = {hA, hB};
  for (int L = 0; L < 3; ++L) {
    float* hpre = bufs[L & 1];
    if (L == 0)
      gather_kernel<0><<<NN * 32 / 256, 256, 0, stream>>>(cur, eidx, offs, nullptr, agg);
    else
      gather_kernel<1><<<NN * 32 / 256, 256, 0, stream>>>(cur, eidx, offs, sc, agg);
    hipMemsetAsync(sums, 0, 256 * sizeof(float), stream);
    if (L == 0)
      gemm_fused<0><<<NN / 32, 256, 0, stream>>>(agg, cur, nullptr, Wl[L], bl[L], Wr[L],
                                                 hpre, sums);
    else
      gemm_fused<1><<<NN / 32, 256, 0, stream>>>(agg, cur, sc, Wl[L], bl[L], Wr[L],
                                                 hpre, sums);
    bn_params<<<1, 128, 0, stream>>>(sums, g[L], bb[L], sc);
    cur = hpre;
  }
  // layer 4 + log_softmax (h-side BN applied in-kernel, agg-side applied in gather)
  gather_kernel<1><<<NN * 32 / 256, 256, 0, stream>>>(cur, eidx, offs, sc, agg);
  final_kernel<<<NN / FROWS, 256, 0, stream>>>(agg, cur, sc, Wl[3], bl[3], Wr[3],
                                               (float*)d_out);
}

// Round 5
// 990.602 us; speedup vs baseline: 1.2454x; 1.0622x over previous
//
#include <hip/hip_runtime.h>
#include <math.h>

#define NN 100000
#define NE 800000
#define F 128
#define KK 256
#define OUTD 40
#define EPSF 1e-5f
#define NB 391   // ceil(NN/256)
#define FROWS 32 // rows per block in final kernel

// ---------------- edge_index dtype normalization ----------------
__global__ void detect_kernel(const int* __restrict__ ei_raw, int* __restrict__ flag) {
  __shared__ int any;
  if (threadIdx.x == 0) any = 0;
  __syncthreads();
  if (ei_raw[2 * threadIdx.x + 1] != 0) atomicOr(&any, 1);
  __syncthreads();
  if (threadIdx.x == 0) *flag = (any == 0) ? 1 : 0;  // 1 => int64 source
}

__global__ __launch_bounds__(256) void conv_kernel(const int* __restrict__ ei_raw,
                                                   const int* __restrict__ flag,
                                                   int* __restrict__ es) {
  int i = blockIdx.x * 256 + threadIdx.x;
  if (i < 2 * NE) {
    int f = *flag;
    es[i] = f ? ei_raw[2 * i] : ei_raw[i];
  }
}

// ---------------- CSR build (dst-keyed, stores src) ----------------
__global__ __launch_bounds__(256) void deg_kernel(const int* __restrict__ dst,
                                                  int* __restrict__ deg) {
  int e = blockIdx.x * 256 + threadIdx.x;
  if (e < NE) atomicAdd(&deg[dst[e]], 1);
}

__global__ __launch_bounds__(256) void scan1(const int* __restrict__ deg,
                                             int* __restrict__ offs,
                                             int* __restrict__ bsum) {
  __shared__ int sh[256];
  const int tid = threadIdx.x;
  const int i = blockIdx.x * 256 + tid;
  int v = (i < NN) ? deg[i] : 0;
  sh[tid] = v;
  __syncthreads();
#pragma unroll
  for (int off = 1; off < 256; off <<= 1) {
    int add = (tid >= off) ? sh[tid - off] : 0;
    __syncthreads();
    sh[tid] += add;
    __syncthreads();
  }
  if (i < NN) offs[i] = sh[tid] - v;  // exclusive
  if (tid == 255) bsum[blockIdx.x] = sh[255];
}

__global__ void scan2(int* __restrict__ bsum) {
  __shared__ int sh[512];
  const int t = threadIdx.x;
  int v = (t < NB) ? bsum[t] : 0;
  sh[t] = v;
  __syncthreads();
#pragma unroll
  for (int off = 1; off < 512; off <<= 1) {
    int add = (t >= off) ? sh[t - off] : 0;
    __syncthreads();
    sh[t] += add;
    __syncthreads();
  }
  if (t < NB) bsum[t] = sh[t] - v;  // exclusive block offsets
}

__global__ __launch_bounds__(256) void scan3(int* __restrict__ offs,
                                             int* __restrict__ woff,
                                             const int* __restrict__ bsum) {
  int i = blockIdx.x * 256 + threadIdx.x;
  if (i < NN) {
    int o = offs[i] + bsum[blockIdx.x];
    offs[i] = o;
    woff[i] = o;
  }
  if (i == 0) offs[NN] = NE;
}

__global__ __launch_bounds__(256) void fill_kernel(const int* __restrict__ src,
                                                   const int* __restrict__ dst,
                                                   int* __restrict__ woff,
                                                   int* __restrict__ eidx) {
  int e = blockIdx.x * 256 + threadIdx.x;
  if (e < NE) {
    int pos = atomicAdd(&woff[dst[e]], 1);
    eidx[pos] = src[e];
  }
}

// ---------------- W4 transpose: Wt[j][k] over concat-K ----------------
__global__ __launch_bounds__(256) void transpose_w(const float* __restrict__ Wl,
                                                   const float* __restrict__ Wr,
                                                   float* __restrict__ Wt) {
  int i = blockIdx.x * 256 + threadIdx.x;  // OUTD*KK
  if (i < OUTD * KK) {
    int j = i / KK, k = i - j * KK;
    Wt[i] = (k < F) ? Wl[k * OUTD + j] : Wr[(k - F) * OUTD + j];
  }
}

// ---------------- gather-based mean aggregation (+ fused BN/ReLU of source) ----
// 32 lanes per node row; each lane owns one float4 column slice. 8-edge unroll
// puts 8 independent 16B gathers in flight per lane (deg mean = 8).
template <int BN>
__global__ __launch_bounds__(256) void gather_kernel(const float* __restrict__ xin,
                                                     const int* __restrict__ eidx,
                                                     const int* __restrict__ offs,
                                                     const float* __restrict__ sc,
                                                     float* __restrict__ agg) {
  int tid = blockIdx.x * 256 + threadIdx.x;
  int n = tid >> 5;
  int q = tid & 31;
  int beg = offs[n];
  int end = offs[n + 1];
  float4 scl, shf;
  if (BN) {
    scl = *(const float4*)(sc + q * 4);
    shf = *(const float4*)(sc + 128 + q * 4);
  }
  float ax = 0.f, ay = 0.f, az = 0.f, aw = 0.f;
#define ACCV(vv)                                         \
  do {                                                   \
    if (BN) {                                            \
      vv.x = fmaxf(fmaf(vv.x, scl.x, shf.x), 0.f);       \
      vv.y = fmaxf(fmaf(vv.y, scl.y, shf.y), 0.f);       \
      vv.z = fmaxf(fmaf(vv.z, scl.z, shf.z), 0.f);       \
      vv.w = fmaxf(fmaf(vv.w, scl.w, shf.w), 0.f);       \
    }                                                    \
    ax += vv.x; ay += vv.y; az += vv.z; aw += vv.w;      \
  } while (0)
  int i = beg;
  for (; i + 8 <= end; i += 8) {
    int s0 = eidx[i],     s1 = eidx[i + 1], s2 = eidx[i + 2], s3 = eidx[i + 3];
    int s4 = eidx[i + 4], s5 = eidx[i + 5], s6 = eidx[i + 6], s7 = eidx[i + 7];
    float4 v0 = *(const float4*)(xin + (size_t)s0 * F + q * 4);
    float4 v1 = *(const float4*)(xin + (size_t)s1 * F + q * 4);
    float4 v2 = *(const float4*)(xin + (size_t)s2 * F + q * 4);
    float4 v3 = *(const float4*)(xin + (size_t)s3 * F + q * 4);
    float4 v4 = *(const float4*)(xin + (size_t)s4 * F + q * 4);
    float4 v5 = *(const float4*)(xin + (size_t)s5 * F + q * 4);
    float4 v6 = *(const float4*)(xin + (size_t)s6 * F + q * 4);
    float4 v7 = *(const float4*)(xin + (size_t)s7 * F + q * 4);
    ACCV(v0); ACCV(v1); ACCV(v2); ACCV(v3);
    ACCV(v4); ACCV(v5); ACCV(v6); ACCV(v7);
  }
  for (; i + 2 <= end; i += 2) {
    int s0 = eidx[i], s1 = eidx[i + 1];
    float4 v0 = *(const float4*)(xin + (size_t)s0 * F + q * 4);
    float4 v1 = *(const float4*)(xin + (size_t)s1 * F + q * 4);
    ACCV(v0); ACCV(v1);
  }
  if (i < end) {
    int s0 = eidx[i];
    float4 v0 = *(const float4*)(xin + (size_t)s0 * F + q * 4);
    ACCV(v0);
  }
#undef ACCV
  float m = 1.0f / fmaxf((float)(end - beg), 1.0f);
  float4 o;
  o.x = ax * m; o.y = ay * m; o.z = az * m; o.w = aw * m;
  *(float4*)(agg + (size_t)n * F + q * 4) = o;
}

// ------ fused dual GEMM: out = agg@Wl + bl + bnrelu(x)@Wr, + BN-stats epilogue ----
template <int BN>
__global__ __launch_bounds__(256) void gemm_fused(const float* __restrict__ agg,
                                                  const float* __restrict__ xin,
                                                  const float* __restrict__ sc,
                                                  const float* __restrict__ Wl,
                                                  const float* __restrict__ bl,
                                                  const float* __restrict__ Wr,
                                                  float* __restrict__ out,
                                                  float* __restrict__ sums) {
  __shared__ float tile[32][KK];  // 32 KB
  const int t = threadIdx.x;
  const int row0 = blockIdx.x * 32;
#pragma unroll
  for (int i = 0; i < 8; ++i) {
    int slot = t + i * 256;      // 0..2047
    int r = slot >> 6;           // tile row
    int c4 = slot & 63;          // float4 column
    int row = row0 + r;
    float4 v;
    if (c4 < 32) {
      v = *(const float4*)(agg + (size_t)row * F + c4 * 4);  // already BN'd/mean'd
    } else {
      int c = (c4 - 32) * 4;
      v = *(const float4*)(xin + (size_t)row * F + c);
      if (BN) {
        float4 s4 = *(const float4*)(sc + c);
        float4 b4 = *(const float4*)(sc + 128 + c);
        v.x = fmaxf(fmaf(v.x, s4.x, b4.x), 0.f);
        v.y = fmaxf(fmaf(v.y, s4.y, b4.y), 0.f);
        v.z = fmaxf(fmaf(v.z, s4.z, b4.z), 0.f);
        v.w = fmaxf(fmaf(v.w, s4.w, b4.w), 0.f);
      }
    }
    *(float4*)(&tile[r][c4 * 4]) = v;
  }
  __syncthreads();

  const int tx = t & 31;   // column group (4 cols)
  const int ty = t >> 5;   // row group (4 rows)
  float acc[4][4];
#pragma unroll
  for (int r = 0; r < 4; ++r)
#pragma unroll
    for (int c = 0; c < 4; ++c) acc[r][c] = 0.f;

#pragma unroll 1
  for (int half = 0; half < 2; ++half) {
    const float* __restrict__ Wp = half ? Wr : Wl;
    const int kb = half * 128;
    for (int k = 0; k < 128; k += 4) {
      float4 in4[4];
#pragma unroll
      for (int r = 0; r < 4; ++r)
        in4[r] = *(const float4*)(&tile[ty * 4 + r][kb + k]);
#pragma unroll
      for (int i = 0; i < 4; ++i) {
        float4 w = *(const float4*)(Wp + (size_t)(k + i) * F + tx * 4);
        float a[4];
        a[0] = ((const float*)&in4[0])[i];
        a[1] = ((const float*)&in4[1])[i];
        a[2] = ((const float*)&in4[2])[i];
        a[3] = ((const float*)&in4[3])[i];
#pragma unroll
        for (int r = 0; r < 4; ++r) {
          acc[r][0] = fmaf(a[r], w.x, acc[r][0]);
          acc[r][1] = fmaf(a[r], w.y, acc[r][1]);
          acc[r][2] = fmaf(a[r], w.z, acc[r][2]);
          acc[r][3] = fmaf(a[r], w.w, acc[r][3]);
        }
      }
    }
  }
  float4 b4 = *(const float4*)(bl + tx * 4);
  float ps[4] = {0.f, 0.f, 0.f, 0.f};
  float pq[4] = {0.f, 0.f, 0.f, 0.f};
#pragma unroll
  for (int r = 0; r < 4; ++r) {
    float4 o;
    o.x = acc[r][0] + b4.x;
    o.y = acc[r][1] + b4.y;
    o.z = acc[r][2] + b4.z;
    o.w = acc[r][3] + b4.w;
    ps[0] += o.x; pq[0] = fmaf(o.x, o.x, pq[0]);
    ps[1] += o.y; pq[1] = fmaf(o.y, o.y, pq[1]);
    ps[2] += o.z; pq[2] = fmaf(o.z, o.z, pq[2]);
    ps[3] += o.w; pq[3] = fmaf(o.w, o.w, pq[3]);
    *(float4*)(out + (size_t)(row0 + ty * 4 + r) * F + tx * 4) = o;
  }
  // BN-stats epilogue: per-column block partials -> LDS reduce -> atomics
  __syncthreads();
  float* red = &tile[0][0];  // reuse: [2][8][128] floats = 8 KB
#pragma unroll
  for (int j = 0; j < 4; ++j) {
    red[ty * 128 + tx * 4 + j] = ps[j];
    red[2048 + ty * 128 + tx * 4 + j] = pq[j];
  }
  __syncthreads();
  if (t < 128) {
    float s = 0.f, qq = 0.f;
#pragma unroll
    for (int g2 = 0; g2 < 8; ++g2) {
      s += red[g2 * 128 + t];
      qq += red[2048 + g2 * 128 + t];
    }
    atomicAdd(&sums[t], s);
    atomicAdd(&sums[128 + t], qq);
  }
}

// ---------------- BN parameter computation ----------------
__global__ void bn_params(const float* __restrict__ sums, const float* __restrict__ g,
                          const float* __restrict__ b, float* __restrict__ sc) {
  int c = threadIdx.x;  // 128
  float mu = sums[c] * (1.0f / NN);
  float var = sums[128 + c] * (1.0f / NN) - mu * mu;
  float scale = g[c] * rsqrtf(var + EPSF);
  sc[c] = scale;
  sc[128 + c] = b[c] - mu * scale;
}

// ------- final layer v2: 32-row LDS tile, W^T from global, fused log_softmax ----
// 4 waves x 8 rows; lane tx = output column (40 active); tile reads are
// wave-uniform broadcasts (conflict-free); W column read as float4 from Wt.
__global__ __launch_bounds__(256) void final_kernel(const float* __restrict__ agg,
                                                    const float* __restrict__ h,
                                                    const float* __restrict__ sc,
                                                    const float* __restrict__ Wt,
                                                    const float* __restrict__ bl,
                                                    float* __restrict__ out) {
  __shared__ float tile[FROWS][KK];  // 32 KB
  const int t = threadIdx.x;
  const int row0 = blockIdx.x * FROWS;
#pragma unroll
  for (int i = 0; i < 8; ++i) {
    int slot = t + i * 256;  // 0..2047
    int r = slot >> 6, c4 = slot & 63;
    int row = row0 + r;
    float4 v;
    if (c4 < 32) {
      v = *(const float4*)(agg + (size_t)row * F + c4 * 4);
    } else {
      int c = (c4 - 32) * 4;
      v = *(const float4*)(h + (size_t)row * F + c);
      float4 s4 = *(const float4*)(sc + c);
      float4 b4 = *(const float4*)(sc + 128 + c);
      v.x = fmaxf(fmaf(v.x, s4.x, b4.x), 0.f);
      v.y = fmaxf(fmaf(v.y, s4.y, b4.y), 0.f);
      v.z = fmaxf(fmaf(v.z, s4.z, b4.z), 0.f);
      v.w = fmaxf(fmaf(v.w, s4.w, b4.w), 0.f);
    }
    *(float4*)(&tile[r][c4 * 4]) = v;
  }
  __syncthreads();
  const int tx = t & 63;   // output column (40 active)
  const int wv = t >> 6;   // wave id: rows wv*8 .. wv*8+7
  const int jj = (tx < OUTD) ? tx : 0;
  const float* __restrict__ wrow = Wt + (size_t)jj * KK;
  float acc[8] = {0.f, 0.f, 0.f, 0.f, 0.f, 0.f, 0.f, 0.f};
#pragma unroll 2
  for (int k = 0; k < KK; k += 4) {
    float4 w = *(const float4*)(wrow + k);
#pragma unroll
    for (int r = 0; r < 8; ++r) {
      float4 a = *(const float4*)(&tile[wv * 8 + r][k]);  // wave-uniform broadcast
      acc[r] = fmaf(a.x, w.x, acc[r]);
      acc[r] = fmaf(a.y, w.y, acc[r]);
      acc[r] = fmaf(a.z, w.z, acc[r]);
      acc[r] = fmaf(a.w, w.w, acc[r]);
    }
  }
  float bias = bl[jj];
#pragma unroll
  for (int r = 0; r < 8; ++r) {
    float v = acc[r] + bias;
    float m = (tx < OUTD) ? v : -INFINITY;
#pragma unroll
    for (int off = 32; off > 0; off >>= 1) m = fmaxf(m, __shfl_xor(m, off));
    float e = (tx < OUTD) ? expf(v - m) : 0.f;
    float s = e;
#pragma unroll
    for (int off = 32; off > 0; off >>= 1) s += __shfl_xor(s, off);
    if (tx < OUTD) out[(size_t)(row0 + wv * 8 + r) * OUTD + tx] = v - m - logf(s);
  }
}

// ---------------- driver ----------------
extern "C" void kernel_launch(void* const* d_in, const int* in_sizes, int n_in,
                              void* d_out, int out_size, void* d_ws, size_t ws_size,
                              hipStream_t stream) {
  const float* x = (const float*)d_in[0];
  const int* ei_raw = (const int*)d_in[1];
  const float* Wl[4] = {(const float*)d_in[2], (const float*)d_in[5],
                        (const float*)d_in[8], (const float*)d_in[11]};
  const float* bl[4] = {(const float*)d_in[3], (const float*)d_in[6],
                        (const float*)d_in[9], (const float*)d_in[12]};
  const float* Wr[4] = {(const float*)d_in[4], (const float*)d_in[7],
                        (const float*)d_in[10], (const float*)d_in[13]};
  const float* g[3] = {(const float*)d_in[14], (const float*)d_in[16],
                       (const float*)d_in[18]};
  const float* bb[3] = {(const float*)d_in[15], (const float*)d_in[17],
                        (const float*)d_in[19]};

  char* wsb = (char*)d_ws;
  float* agg = (float*)wsb;                       wsb += (size_t)NN * F * 4;
  float* hA  = (float*)wsb;                       wsb += (size_t)NN * F * 4;
  float* hB  = (float*)wsb;                       wsb += (size_t)NN * F * 4;
  int* es    = (int*)wsb;                         wsb += (size_t)2 * NE * 4;
  int* eidx  = (int*)wsb;                         wsb += (size_t)NE * 4;
  int* offs  = (int*)wsb;                         wsb += (size_t)(NN + 64) * 4;
  int* woff  = (int*)wsb;                         wsb += (size_t)(NN + 64) * 4;
  int* bsum  = (int*)wsb;                         wsb += 512 * 4;
  float* sums = (float*)wsb;                      wsb += 256 * 4;
  float* sc   = (float*)wsb;                      wsb += 256 * 4;
  float* Wt   = (float*)wsb;                      wsb += (size_t)OUTD * KK * 4;
  int* flag   = (int*)wsb;                        wsb += 256;

  int* esrc = es;
  int* edst = es + NE;

  // --- edge_index normalization (int64 vs int32) ---
  detect_kernel<<<1, 256, 0, stream>>>(ei_raw, flag);
  conv_kernel<<<(2 * NE + 255) / 256, 256, 0, stream>>>(ei_raw, flag, es);

  // --- CSR build (dst-keyed) + W4 transpose ---
  hipMemsetAsync(woff, 0, NN * sizeof(int), stream);
  deg_kernel<<<NE / 256, 256, 0, stream>>>(edst, woff);
  scan1<<<NB, 256, 0, stream>>>(woff, offs, bsum);
  scan2<<<1, 512, 0, stream>>>(bsum);
  scan3<<<NB, 256, 0, stream>>>(offs, woff, bsum);
  fill_kernel<<<NE / 256, 256, 0, stream>>>(esrc, edst, woff, eidx);
  transpose_w<<<(OUTD * KK + 255) / 256, 256, 0, stream>>>(Wl[3], Wr[3], Wt);

  const float* cur = x;
  float* bufs[2] = {hA, hB};
  for (int L = 0; L < 3; ++L) {
    float* hpre = bufs[L & 1];
    if (L == 0)
      gather_kernel<0><<<NN * 32 / 256, 256, 0, stream>>>(cur, eidx, offs, nullptr, agg);
    else
      gather_kernel<1><<<NN * 32 / 256, 256, 0, stream>>>(cur, eidx, offs, sc, agg);
    hipMemsetAsync(sums, 0, 256 * sizeof(float), stream);
    if (L == 0)
      gemm_fused<0><<<NN / 32, 256, 0, stream>>>(agg, cur, nullptr, Wl[L], bl[L], Wr[L],
                                                 hpre, sums);
    else
      gemm_fused<1><<<NN / 32, 256, 0, stream>>>(agg, cur, sc, Wl[L], bl[L], Wr[L],
                                                 hpre, sums);
    bn_params<<<1, 128, 0, stream>>>(sums, g[L], bb[L], sc);
    cur = hpre;
  }
  // layer 4 + log_softmax (h-side BN applied in-kernel, agg-side applied in gather)
  gather_kernel<1><<<NN * 32 / 256, 256, 0, stream>>>(cur, eidx, offs, sc, agg);
  final_kernel<<<NN / FROWS, 256, 0, stream>>>(agg, cur, sc, Wt, bl[3],
                                               (float*)d_out);
}

// Round 7
// 874.962 us; speedup vs baseline: 1.4100x; 1.1322x over previous
//
#include <hip/hip_runtime.h>
#include <math.h>

#define NN 100000
#define NE 800000
#define F 128
#define KK 256
#define OUTD 40
#define EPSF 1e-5f
#define NB 391   // ceil(NN/256)

// ---------------- edge_index dtype normalization ----------------
__global__ void detect_kernel(const int* __restrict__ ei_raw, int* __restrict__ flag) {
  __shared__ int any;
  if (threadIdx.x == 0) any = 0;
  __syncthreads();
  if (ei_raw[2 * threadIdx.x + 1] != 0) atomicOr(&any, 1);
  __syncthreads();
  if (threadIdx.x == 0) *flag = (any == 0) ? 1 : 0;  // 1 => int64 source
}

__global__ __launch_bounds__(256) void conv_kernel(const int* __restrict__ ei_raw,
                                                   const int* __restrict__ flag,
                                                   int* __restrict__ es) {
  int i = blockIdx.x * 256 + threadIdx.x;
  if (i < 2 * NE) {
    int f = *flag;
    es[i] = f ? ei_raw[2 * i] : ei_raw[i];
  }
}

// ---------------- CSR build (dst-keyed, stores src) ----------------
__global__ __launch_bounds__(256) void deg_kernel(const int* __restrict__ dst,
                                                  int* __restrict__ deg) {
  int e = blockIdx.x * 256 + threadIdx.x;
  if (e < NE) atomicAdd(&deg[dst[e]], 1);
}

__global__ __launch_bounds__(256) void scan1(const int* __restrict__ deg,
                                             int* __restrict__ offs,
                                             int* __restrict__ bsum) {
  __shared__ int sh[256];
  const int tid = threadIdx.x;
  const int i = blockIdx.x * 256 + tid;
  int v = (i < NN) ? deg[i] : 0;
  sh[tid] = v;
  __syncthreads();
#pragma unroll
  for (int off = 1; off < 256; off <<= 1) {
    int add = (tid >= off) ? sh[tid - off] : 0;
    __syncthreads();
    sh[tid] += add;
    __syncthreads();
  }
  if (i < NN) offs[i] = sh[tid] - v;  // exclusive
  if (tid == 255) bsum[blockIdx.x] = sh[255];
}

__global__ void scan2(int* __restrict__ bsum) {
  __shared__ int sh[512];
  const int t = threadIdx.x;
  int v = (t < NB) ? bsum[t] : 0;
  sh[t] = v;
  __syncthreads();
#pragma unroll
  for (int off = 1; off < 512; off <<= 1) {
    int add = (t >= off) ? sh[t - off] : 0;
    __syncthreads();
    sh[t] += add;
    __syncthreads();
  }
  if (t < NB) bsum[t] = sh[t] - v;  // exclusive block offsets
}

__global__ __launch_bounds__(256) void scan3(int* __restrict__ offs,
                                             int* __restrict__ woff,
                                             const int* __restrict__ bsum) {
  int i = blockIdx.x * 256 + threadIdx.x;
  if (i < NN) {
    int o = offs[i] + bsum[blockIdx.x];
    offs[i] = o;
    woff[i] = o;
  }
  if (i == 0) offs[NN] = NE;
}

__global__ __launch_bounds__(256) void fill_kernel(const int* __restrict__ src,
                                                   const int* __restrict__ dst,
                                                   int* __restrict__ woff,
                                                   int* __restrict__ eidx) {
  int e = blockIdx.x * 256 + threadIdx.x;
  if (e < NE) {
    int pos = atomicAdd(&woff[dst[e]], 1);
    eidx[pos] = src[e];
  }
}

// ---------------- W4 transpose: Wt[j][k] over concat-K ----------------
__global__ __launch_bounds__(256) void transpose_w(const float* __restrict__ Wl,
                                                   const float* __restrict__ Wr,
                                                   float* __restrict__ Wt) {
  int i = blockIdx.x * 256 + threadIdx.x;  // OUTD*KK
  if (i < OUTD * KK) {
    int j = i / KK, k = i - j * KK;
    Wt[i] = (k < F) ? Wl[k * OUTD + j] : Wr[(k - F) * OUTD + j];
  }
}

// ---------------- shared helpers ----------------
__device__ __forceinline__ void bnrelu4(float4& v, const float4& s, const float4& b) {
  v.x = fmaxf(fmaf(v.x, s.x, b.x), 0.f);
  v.y = fmaxf(fmaf(v.y, s.y, b.y), 0.f);
  v.z = fmaxf(fmaf(v.z, s.z, b.z), 0.f);
  v.w = fmaxf(fmaf(v.w, s.w, b.w), 0.f);
}

// gather-mean phase: 8 groups x 32 lanes; each group owns 4 tile rows.
template <int BN>
__device__ __forceinline__ void gather_phase(float (*tile)[F],
                                             const float* __restrict__ hin,
                                             const int* __restrict__ eidx,
                                             const int* __restrict__ offs,
                                             int row0, int q, int grp,
                                             const float4& scl, const float4& shf) {
#pragma unroll 1
  for (int rr = 0; rr < 4; ++rr) {
    int r = grp * 4 + rr;
    int n = row0 + r;
    int beg = offs[n];
    int end = offs[n + 1];
    float ax = 0.f, ay = 0.f, az = 0.f, aw = 0.f;
#define ACCV(vv)                                       \
  do {                                                 \
    if (BN) bnrelu4(vv, scl, shf);                     \
    ax += vv.x; ay += vv.y; az += vv.z; aw += vv.w;    \
  } while (0)
    int i = beg;
    for (; i + 4 <= end; i += 4) {
      int s0 = eidx[i], s1 = eidx[i + 1], s2 = eidx[i + 2], s3 = eidx[i + 3];
      float4 v0 = *(const float4*)(hin + (size_t)s0 * F + q * 4);
      float4 v1 = *(const float4*)(hin + (size_t)s1 * F + q * 4);
      float4 v2 = *(const float4*)(hin + (size_t)s2 * F + q * 4);
      float4 v3 = *(const float4*)(hin + (size_t)s3 * F + q * 4);
      ACCV(v0); ACCV(v1); ACCV(v2); ACCV(v3);
    }
    for (; i < end; ++i) {
      int s0 = eidx[i];
      float4 v0 = *(const float4*)(hin + (size_t)s0 * F + q * 4);
      ACCV(v0);
    }
#undef ACCV
    float m = 1.0f / fmaxf((float)(end - beg), 1.0f);
    float4 o;
    o.x = ax * m; o.y = ay * m; o.z = az * m; o.w = aw * m;
    *(float4*)(&tile[r][q * 4]) = o;
  }
}

// root-load phase: stream 32 rows of hin (bnrelu'd) into tile.
template <int BN>
__device__ __forceinline__ void root_phase(float (*tile)[F],
                                           const float* __restrict__ hin,
                                           int row0, int q, int grp,
                                           const float4& scl, const float4& shf) {
#pragma unroll
  for (int rr = 0; rr < 4; ++rr) {
    int r = grp * 4 + rr;
    float4 v = *(const float4*)(hin + (size_t)(row0 + r) * F + q * 4);
    if (BN) bnrelu4(v, scl, shf);
    *(float4*)(&tile[r][q * 4]) = v;
  }
}

// one K=128 FMA half: acc += tile @ Wp   (tile rows broadcast, W from global)
__device__ __forceinline__ void fma_half(const float (*tile)[F],
                                         const float* __restrict__ Wp,
                                         int tx, int ty, float acc[4][4]) {
  for (int k = 0; k < F; k += 4) {
    float4 in4[4];
#pragma unroll
    for (int r = 0; r < 4; ++r)
      in4[r] = *(const float4*)(&tile[ty * 4 + r][k]);
#pragma unroll
    for (int i = 0; i < 4; ++i) {
      float4 w = *(const float4*)(Wp + (size_t)(k + i) * F + tx * 4);
      float a[4];
      a[0] = ((const float*)&in4[0])[i];
      a[1] = ((const float*)&in4[1])[i];
      a[2] = ((const float*)&in4[2])[i];
      a[3] = ((const float*)&in4[3])[i];
#pragma unroll
      for (int r = 0; r < 4; ++r) {
        acc[r][0] = fmaf(a[r], w.x, acc[r][0]);
        acc[r][1] = fmaf(a[r], w.y, acc[r][1]);
        acc[r][2] = fmaf(a[r], w.z, acc[r][2]);
        acc[r][3] = fmaf(a[r], w.w, acc[r][3]);
      }
    }
  }
}

// ------ fused layer: gather-mean + dual GEMM + bias + BN-stats epilogue ------
// Phase A: gather agg tile (16KB LDS), FMA with Wl. Phase B: root tile, FMA Wr.
template <int BN>
__global__ __launch_bounds__(256) void fused_layer(const float* __restrict__ hin,
                                                   const int* __restrict__ eidx,
                                                   const int* __restrict__ offs,
                                                   const float* __restrict__ sc,
                                                   const float* __restrict__ Wl,
                                                   const float* __restrict__ bl,
                                                   const float* __restrict__ Wr,
                                                   float* __restrict__ out,
                                                   float* __restrict__ sums) {
  __shared__ float tile[32][F];  // 16 KB
  const int t = threadIdx.x;
  const int row0 = blockIdx.x * 32;
  const int q = t & 31;
  const int grp = t >> 5;
  float4 scl, shf;
  if (BN) {
    scl = *(const float4*)(sc + q * 4);
    shf = *(const float4*)(sc + 128 + q * 4);
  }

  gather_phase<BN>(tile, hin, eidx, offs, row0, q, grp, scl, shf);
  __syncthreads();

  const int tx = t & 31;
  const int ty = t >> 5;
  float acc[4][4];
#pragma unroll
  for (int r = 0; r < 4; ++r)
#pragma unroll
    for (int c = 0; c < 4; ++c) acc[r][c] = 0.f;

  fma_half(tile, Wl, tx, ty, acc);
  __syncthreads();  // done reading agg tile

  root_phase<BN>(tile, hin, row0, q, grp, scl, shf);
  __syncthreads();

  fma_half(tile, Wr, tx, ty, acc);

  float4 b4 = *(const float4*)(bl + tx * 4);
  float ps[4] = {0.f, 0.f, 0.f, 0.f};
  float pq[4] = {0.f, 0.f, 0.f, 0.f};
#pragma unroll
  for (int r = 0; r < 4; ++r) {
    float4 o;
    o.x = acc[r][0] + b4.x;
    o.y = acc[r][1] + b4.y;
    o.z = acc[r][2] + b4.z;
    o.w = acc[r][3] + b4.w;
    ps[0] += o.x; pq[0] = fmaf(o.x, o.x, pq[0]);
    ps[1] += o.y; pq[1] = fmaf(o.y, o.y, pq[1]);
    ps[2] += o.z; pq[2] = fmaf(o.z, o.z, pq[2]);
    ps[3] += o.w; pq[3] = fmaf(o.w, o.w, pq[3]);
    *(float4*)(out + (size_t)(row0 + ty * 4 + r) * F + tx * 4) = o;
  }
  // BN-stats epilogue: per-column block partials -> LDS reduce -> atomics
  __syncthreads();  // done reading tile; reuse as scratch
  float* red = &tile[0][0];  // [2][8][128] floats = 8 KB
#pragma unroll
  for (int j = 0; j < 4; ++j) {
    red[ty * 128 + tx * 4 + j] = ps[j];
    red[2048 + ty * 128 + tx * 4 + j] = pq[j];
  }
  __syncthreads();
  if (t < 128) {
    float s = 0.f, qq = 0.f;
#pragma unroll
    for (int g2 = 0; g2 < 8; ++g2) {
      s += red[g2 * 128 + t];
      qq += red[2048 + g2 * 128 + t];
    }
    atomicAdd(&sums[t], s);
    atomicAdd(&sums[128 + t], qq);
  }
}

// ---------------- BN parameter computation ----------------
__global__ void bn_params(const float* __restrict__ sums, const float* __restrict__ g,
                          const float* __restrict__ b, float* __restrict__ sc) {
  int c = threadIdx.x;  // 128
  float mu = sums[c] * (1.0f / NN);
  float var = sums[128 + c] * (1.0f / NN) - mu * mu;
  float scale = g[c] * rsqrtf(var + EPSF);
  sc[c] = scale;
  sc[128 + c] = b[c] - mu * scale;
}

// ------ fused final: gather-mean + [K=256 -> 40] GEMM + log_softmax ----------
// Two K-half passes over a 16KB tile; W^T rows from global (L1-resident).
__global__ __launch_bounds__(256) void fused_final(const float* __restrict__ hin,
                                                   const int* __restrict__ eidx,
                                                   const int* __restrict__ offs,
                                                   const float* __restrict__ sc,
                                                   const float* __restrict__ Wt,
                                                   const float* __restrict__ bl,
                                                   float* __restrict__ out) {
  __shared__ float tile[32][F];  // 16 KB
  const int t = threadIdx.x;
  const int row0 = blockIdx.x * 32;
  const int q = t & 31;
  const int grp = t >> 5;
  float4 scl = *(const float4*)(sc + q * 4);
  float4 shf = *(const float4*)(sc + 128 + q * 4);

  gather_phase<1>(tile, hin, eidx, offs, row0, q, grp, scl, shf);
  __syncthreads();

  const int tx = t & 63;   // output column (40 active)
  const int wv = t >> 6;   // wave id: rows wv*8 .. wv*8+7
  const int jj = (tx < OUTD) ? tx : 0;
  const float* __restrict__ wrow = Wt + (size_t)jj * KK;
  float acc[8] = {0.f, 0.f, 0.f, 0.f, 0.f, 0.f, 0.f, 0.f};
#pragma unroll 2
  for (int k = 0; k < F; k += 4) {
    float4 w = *(const float4*)(wrow + k);
#pragma unroll
    for (int r = 0; r < 8; ++r) {
      float4 a = *(const float4*)(&tile[wv * 8 + r][k]);  // wave-uniform broadcast
      acc[r] = fmaf(a.x, w.x, acc[r]);
      acc[r] = fmaf(a.y, w.y, acc[r]);
      acc[r] = fmaf(a.z, w.z, acc[r]);
      acc[r] = fmaf(a.w, w.w, acc[r]);
    }
  }
  __syncthreads();  // done reading agg tile

  root_phase<1>(tile, hin, row0, q, grp, scl, shf);
  __syncthreads();

#pragma unroll 2
  for (int k = 0; k < F; k += 4) {
    float4 w = *(const float4*)(wrow + F + k);
#pragma unroll
    for (int r = 0; r < 8; ++r) {
      float4 a = *(const float4*)(&tile[wv * 8 + r][k]);
      acc[r] = fmaf(a.x, w.x, acc[r]);
      acc[r] = fmaf(a.y, w.y, acc[r]);
      acc[r] = fmaf(a.z, w.z, acc[r]);
      acc[r] = fmaf(a.w, w.w, acc[r]);
    }
  }

  float bias = bl[jj];
#pragma unroll
  for (int r = 0; r < 8; ++r) {
    float v = acc[r] + bias;
    float m = (tx < OUTD) ? v : -INFINITY;
#pragma unroll
    for (int off = 32; off > 0; off >>= 1) m = fmaxf(m, __shfl_xor(m, off));
    float e = (tx < OUTD) ? expf(v - m) : 0.f;
    float s = e;
#pragma unroll
    for (int off = 32; off > 0; off >>= 1) s += __shfl_xor(s, off);
    if (tx < OUTD) out[(size_t)(row0 + wv * 8 + r) * OUTD + tx] = v - m - logf(s);
  }
}

// ---------------- driver ----------------
extern "C" void kernel_launch(void* const* d_in, const int* in_sizes, int n_in,
                              void* d_out, int out_size, void* d_ws, size_t ws_size,
                              hipStream_t stream) {
  const float* x = (const float*)d_in[0];
  const int* ei_raw = (const int*)d_in[1];
  const float* Wl[4] = {(const float*)d_in[2], (const float*)d_in[5],
                        (const float*)d_in[8], (const float*)d_in[11]};
  const float* bl[4] = {(const float*)d_in[3], (const float*)d_in[6],
                        (const float*)d_in[9], (const float*)d_in[12]};
  const float* Wr[4] = {(const float*)d_in[4], (const float*)d_in[7],
                        (const float*)d_in[10], (const float*)d_in[13]};
  const float* g[3] = {(const float*)d_in[14], (const float*)d_in[16],
                       (const float*)d_in[18]};
  const float* bb[3] = {(const float*)d_in[15], (const float*)d_in[17],
                        (const float*)d_in[19]};

  char* wsb = (char*)d_ws;
  float* hA  = (float*)wsb;                       wsb += (size_t)NN * F * 4;
  float* hB  = (float*)wsb;                       wsb += (size_t)NN * F * 4;
  int* es    = (int*)wsb;                         wsb += (size_t)2 * NE * 4;
  int* eidx  = (int*)wsb;                         wsb += (size_t)NE * 4;
  int* offs  = (int*)wsb;                         wsb += (size_t)(NN + 64) * 4;
  int* woff  = (int*)wsb;                         wsb += (size_t)(NN + 64) * 4;
  int* bsum  = (int*)wsb;                         wsb += 512 * 4;
  float* sums = (float*)wsb;                      wsb += 256 * 4;
  float* sc   = (float*)wsb;                      wsb += 256 * 4;
  float* Wt   = (float*)wsb;                      wsb += (size_t)OUTD * KK * 4;
  int* flag   = (int*)wsb;                        wsb += 256;

  int* esrc = es;
  int* edst = es + NE;

  // --- edge_index normalization (int64 vs int32) ---
  detect_kernel<<<1, 256, 0, stream>>>(ei_raw, flag);
  conv_kernel<<<(2 * NE + 255) / 256, 256, 0, stream>>>(ei_raw, flag, es);

  // --- CSR build (dst-keyed) + W4 transpose ---
  hipMemsetAsync(woff, 0, NN * sizeof(int), stream);
  deg_kernel<<<NE / 256, 256, 0, stream>>>(edst, woff);
  scan1<<<NB, 256, 0, stream>>>(woff, offs, bsum);
  scan2<<<1, 512, 0, stream>>>(bsum);
  scan3<<<NB, 256, 0, stream>>>(offs, woff, bsum);
  fill_kernel<<<NE / 256, 256, 0, stream>>>(esrc, edst, woff, eidx);
  transpose_w<<<(OUTD * KK + 255) / 256, 256, 0, stream>>>(Wl[3], Wr[3], Wt);

  const float* cur = x;
  float* bufs[2] = {hA, hB};
  for (int L = 0; L < 3; ++L) {
    float* hpre = bufs[L & 1];
    hipMemsetAsync(sums, 0, 256 * sizeof(float), stream);
    if (L == 0)
      fused_layer<0><<<NN / 32, 256, 0, stream>>>(cur, eidx, offs, nullptr, Wl[L],
                                                  bl[L], Wr[L], hpre, sums);
    else
      fused_layer<1><<<NN / 32, 256, 0, stream>>>(cur, eidx, offs, sc, Wl[L], bl[L],
                                                  Wr[L], hpre, sums);
    bn_params<<<1, 128, 0, stream>>>(sums, g[L], bb[L], sc);
    cur = hpre;
  }
  // layer 4 + log_softmax (both BN applications fused in-kernel)
  fused_final<<<NN / 32, 256, 0, stream>>>(cur, eidx, offs, sc, Wt, bl[3],
                                           (float*)d_out);
}

// Round 8
// 834.766 us; speedup vs baseline: 1.4779x; 1.0482x over previous
//
#include <hip/hip_runtime.h>
#include <math.h>

#define NN 100000
#define NE 800000
#define F 128
#define KK 256
#define OUTD 40
#define EPSF 1e-5f
#define NB 391   // ceil(NN/256)
#define LROWS 64 // rows per block in fused_layer
#define NLB 1563 // ceil(NN/64)

// ---------------- edge_index dtype normalization ----------------
__global__ void detect_kernel(const int* __restrict__ ei_raw, int* __restrict__ flag) {
  __shared__ int any;
  if (threadIdx.x == 0) any = 0;
  __syncthreads();
  if (ei_raw[2 * threadIdx.x + 1] != 0) atomicOr(&any, 1);
  __syncthreads();
  if (threadIdx.x == 0) *flag = (any == 0) ? 1 : 0;  // 1 => int64 source
}

__global__ __launch_bounds__(256) void conv_kernel(const int* __restrict__ ei_raw,
                                                   const int* __restrict__ flag,
                                                   int* __restrict__ es) {
  int i = blockIdx.x * 256 + threadIdx.x;
  if (i < 2 * NE) {
    int f = *flag;
    es[i] = f ? ei_raw[2 * i] : ei_raw[i];
  }
}

// ---------------- CSR build (dst-keyed, stores src) ----------------
__global__ __launch_bounds__(256) void deg_kernel(const int* __restrict__ dst,
                                                  int* __restrict__ deg) {
  int e = blockIdx.x * 256 + threadIdx.x;
  if (e < NE) atomicAdd(&deg[dst[e]], 1);
}

__global__ __launch_bounds__(256) void scan1(const int* __restrict__ deg,
                                             int* __restrict__ offs,
                                             int* __restrict__ bsum) {
  __shared__ int sh[256];
  const int tid = threadIdx.x;
  const int i = blockIdx.x * 256 + tid;
  int v = (i < NN) ? deg[i] : 0;
  sh[tid] = v;
  __syncthreads();
#pragma unroll
  for (int off = 1; off < 256; off <<= 1) {
    int add = (tid >= off) ? sh[tid - off] : 0;
    __syncthreads();
    sh[tid] += add;
    __syncthreads();
  }
  if (i < NN) offs[i] = sh[tid] - v;  // exclusive
  if (tid == 255) bsum[blockIdx.x] = sh[255];
}

__global__ void scan2(int* __restrict__ bsum) {
  __shared__ int sh[512];
  const int t = threadIdx.x;
  int v = (t < NB) ? bsum[t] : 0;
  sh[t] = v;
  __syncthreads();
#pragma unroll
  for (int off = 1; off < 512; off <<= 1) {
    int add = (t >= off) ? sh[t - off] : 0;
    __syncthreads();
    sh[t] += add;
    __syncthreads();
  }
  if (t < NB) bsum[t] = sh[t] - v;  // exclusive block offsets
}

__global__ __launch_bounds__(256) void scan3(int* __restrict__ offs,
                                             int* __restrict__ woff,
                                             const int* __restrict__ bsum) {
  int i = blockIdx.x * 256 + threadIdx.x;
  if (i < NN) {
    int o = offs[i] + bsum[blockIdx.x];
    offs[i] = o;
    woff[i] = o;
  }
  if (i == 0) offs[NN] = NE;
}

__global__ __launch_bounds__(256) void fill_kernel(const int* __restrict__ src,
                                                   const int* __restrict__ dst,
                                                   int* __restrict__ woff,
                                                   int* __restrict__ eidx) {
  int e = blockIdx.x * 256 + threadIdx.x;
  if (e < NE) {
    int pos = atomicAdd(&woff[dst[e]], 1);
    eidx[pos] = src[e];
  }
}

// ---------------- W4 transpose: Wt[j][k] over concat-K ----------------
__global__ __launch_bounds__(256) void transpose_w(const float* __restrict__ Wl,
                                                   const float* __restrict__ Wr,
                                                   float* __restrict__ Wt) {
  int i = blockIdx.x * 256 + threadIdx.x;  // OUTD*KK
  if (i < OUTD * KK) {
    int j = i / KK, k = i - j * KK;
    Wt[i] = (k < F) ? Wl[k * OUTD + j] : Wr[(k - F) * OUTD + j];
  }
}

// ---------------- shared helpers ----------------
__device__ __forceinline__ void bnrelu4(float4& v, const float4& s, const float4& b) {
  v.x = fmaxf(fmaf(v.x, s.x, b.x), 0.f);
  v.y = fmaxf(fmaf(v.y, s.y, b.y), 0.f);
  v.z = fmaxf(fmaf(v.z, s.z, b.z), 0.f);
  v.w = fmaxf(fmaf(v.w, s.w, b.w), 0.f);
}

// gather-mean of one row's edge list into (ax..aw), 8-deep ILP.
template <int BN>
__device__ __forceinline__ void gather_row(const float* __restrict__ hin,
                                           const int* __restrict__ eidx,
                                           int beg, int end, int q,
                                           const float4& scl, const float4& shf,
                                           float4& out) {
  float ax = 0.f, ay = 0.f, az = 0.f, aw = 0.f;
#define ACCV(vv)                                       \
  do {                                                 \
    if (BN) bnrelu4(vv, scl, shf);                     \
    ax += vv.x; ay += vv.y; az += vv.z; aw += vv.w;    \
  } while (0)
  int i = beg;
  for (; i + 8 <= end; i += 8) {
    int s0 = eidx[i],     s1 = eidx[i + 1], s2 = eidx[i + 2], s3 = eidx[i + 3];
    int s4 = eidx[i + 4], s5 = eidx[i + 5], s6 = eidx[i + 6], s7 = eidx[i + 7];
    float4 v0 = *(const float4*)(hin + (size_t)s0 * F + q * 4);
    float4 v1 = *(const float4*)(hin + (size_t)s1 * F + q * 4);
    float4 v2 = *(const float4*)(hin + (size_t)s2 * F + q * 4);
    float4 v3 = *(const float4*)(hin + (size_t)s3 * F + q * 4);
    float4 v4 = *(const float4*)(hin + (size_t)s4 * F + q * 4);
    float4 v5 = *(const float4*)(hin + (size_t)s5 * F + q * 4);
    float4 v6 = *(const float4*)(hin + (size_t)s6 * F + q * 4);
    float4 v7 = *(const float4*)(hin + (size_t)s7 * F + q * 4);
    ACCV(v0); ACCV(v1); ACCV(v2); ACCV(v3);
    ACCV(v4); ACCV(v5); ACCV(v6); ACCV(v7);
  }
  for (; i + 2 <= end; i += 2) {
    int s0 = eidx[i], s1 = eidx[i + 1];
    float4 v0 = *(const float4*)(hin + (size_t)s0 * F + q * 4);
    float4 v1 = *(const float4*)(hin + (size_t)s1 * F + q * 4);
    ACCV(v0); ACCV(v1);
  }
  if (i < end) {
    int s0 = eidx[i];
    float4 v0 = *(const float4*)(hin + (size_t)s0 * F + q * 4);
    ACCV(v0);
  }
#undef ACCV
  float m = 1.0f / fmaxf((float)(end - beg), 1.0f);
  out.x = ax * m; out.y = ay * m; out.z = az * m; out.w = aw * m;
}

// one K=128 FMA half over a 64-row tile: acc[8][4] += tile @ Wp
__device__ __forceinline__ void fma_half64(const float (*tile)[F],
                                           const float* __restrict__ Wp,
                                           int tx, int ty, float acc[8][4]) {
  for (int k = 0; k < F; k += 4) {
    float4 in4[8];
#pragma unroll
    for (int r = 0; r < 8; ++r)
      in4[r] = *(const float4*)(&tile[ty * 8 + r][k]);
#pragma unroll
    for (int i = 0; i < 4; ++i) {
      float4 w = *(const float4*)(Wp + (size_t)(k + i) * F + tx * 4);
      float a[8];
#pragma unroll
      for (int r = 0; r < 8; ++r) a[r] = ((const float*)&in4[r])[i];
#pragma unroll
      for (int r = 0; r < 8; ++r) {
        acc[r][0] = fmaf(a[r], w.x, acc[r][0]);
        acc[r][1] = fmaf(a[r], w.y, acc[r][1]);
        acc[r][2] = fmaf(a[r], w.z, acc[r][2]);
        acc[r][3] = fmaf(a[r], w.w, acc[r][3]);
      }
    }
  }
}

// ------ fused layer (64-row tile): gather-mean + dual GEMM + BN-stats --------
template <int BN>
__global__ __launch_bounds__(256) void fused_layer(const float* __restrict__ hin,
                                                   const int* __restrict__ eidx,
                                                   const int* __restrict__ offs,
                                                   const float* __restrict__ sc,
                                                   const float* __restrict__ Wl,
                                                   const float* __restrict__ bl,
                                                   const float* __restrict__ Wr,
                                                   float* __restrict__ out,
                                                   float* __restrict__ sums) {
  __shared__ float tile[LROWS][F];  // 32 KB
  const int t = threadIdx.x;
  const int row0 = blockIdx.x * LROWS;
  const int q = t & 31;
  const int grp = t >> 5;  // 8 groups x 8 rows
  float4 scl, shf;
  if (BN) {
    scl = *(const float4*)(sc + q * 4);
    shf = *(const float4*)(sc + 128 + q * 4);
  }

  // phase A: gather-mean 64 rows
#pragma unroll 1
  for (int rr = 0; rr < 8; ++rr) {
    int r = grp * 8 + rr;
    int n = row0 + r;
    float4 o = {0.f, 0.f, 0.f, 0.f};
    if (n < NN) {
      int beg = offs[n];
      int end = offs[n + 1];
      gather_row<BN>(hin, eidx, beg, end, q, scl, shf, o);
    }
    *(float4*)(&tile[r][q * 4]) = o;
  }
  __syncthreads();

  const int tx = t & 31;
  const int ty = t >> 5;
  float acc[8][4];
#pragma unroll
  for (int r = 0; r < 8; ++r)
#pragma unroll
    for (int c = 0; c < 4; ++c) acc[r][c] = 0.f;

  fma_half64(tile, Wl, tx, ty, acc);
  __syncthreads();  // done reading agg tile

  // phase B: root rows
#pragma unroll
  for (int rr = 0; rr < 8; ++rr) {
    int r = grp * 8 + rr;
    int row = row0 + r;
    float4 v = {0.f, 0.f, 0.f, 0.f};
    if (row < NN) {
      v = *(const float4*)(hin + (size_t)row * F + q * 4);
      if (BN) bnrelu4(v, scl, shf);
    }
    *(float4*)(&tile[r][q * 4]) = v;
  }
  __syncthreads();

  fma_half64(tile, Wr, tx, ty, acc);

  float4 b4 = *(const float4*)(bl + tx * 4);
  float ps[4] = {0.f, 0.f, 0.f, 0.f};
  float pq[4] = {0.f, 0.f, 0.f, 0.f};
#pragma unroll
  for (int r = 0; r < 8; ++r) {
    int row = row0 + ty * 8 + r;
    if (row < NN) {
      float4 o;
      o.x = acc[r][0] + b4.x;
      o.y = acc[r][1] + b4.y;
      o.z = acc[r][2] + b4.z;
      o.w = acc[r][3] + b4.w;
      ps[0] += o.x; pq[0] = fmaf(o.x, o.x, pq[0]);
      ps[1] += o.y; pq[1] = fmaf(o.y, o.y, pq[1]);
      ps[2] += o.z; pq[2] = fmaf(o.z, o.z, pq[2]);
      ps[3] += o.w; pq[3] = fmaf(o.w, o.w, pq[3]);
      *(float4*)(out + (size_t)row * F + tx * 4) = o;
    }
  }
  // BN-stats epilogue: per-column block partials -> LDS reduce -> atomics
  __syncthreads();  // done reading tile; reuse as scratch
  float* red = &tile[0][0];  // [2][8][128] floats = 8 KB
#pragma unroll
  for (int j = 0; j < 4; ++j) {
    red[ty * 128 + tx * 4 + j] = ps[j];
    red[2048 + ty * 128 + tx * 4 + j] = pq[j];
  }
  __syncthreads();
  if (t < 128) {
    float s = 0.f, qq = 0.f;
#pragma unroll
    for (int g2 = 0; g2 < 8; ++g2) {
      s += red[g2 * 128 + t];
      qq += red[2048 + g2 * 128 + t];
    }
    atomicAdd(&sums[t], s);
    atomicAdd(&sums[128 + t], qq);
  }
}

// ---------------- BN parameter computation ----------------
__global__ void bn_params(const float* __restrict__ sums, const float* __restrict__ g,
                          const float* __restrict__ b, float* __restrict__ sc) {
  int c = threadIdx.x;  // 128
  float mu = sums[c] * (1.0f / NN);
  float var = sums[128 + c] * (1.0f / NN) - mu * mu;
  float scale = g[c] * rsqrtf(var + EPSF);
  sc[c] = scale;
  sc[128 + c] = b[c] - mu * scale;
}

// ------ fused final: gather-mean + [K=256 -> 40] GEMM + log_softmax ----------
__global__ __launch_bounds__(256) void fused_final(const float* __restrict__ hin,
                                                   const int* __restrict__ eidx,
                                                   const int* __restrict__ offs,
                                                   const float* __restrict__ sc,
                                                   const float* __restrict__ Wt,
                                                   const float* __restrict__ bl,
                                                   float* __restrict__ out) {
  __shared__ float tile[32][F];  // 16 KB
  const int t = threadIdx.x;
  const int row0 = blockIdx.x * 32;
  const int q = t & 31;
  const int grp = t >> 5;
  float4 scl = *(const float4*)(sc + q * 4);
  float4 shf = *(const float4*)(sc + 128 + q * 4);

#pragma unroll 1
  for (int rr = 0; rr < 4; ++rr) {
    int r = grp * 4 + rr;
    int n = row0 + r;
    int beg = offs[n];
    int end = offs[n + 1];
    float4 o;
    gather_row<1>(hin, eidx, beg, end, q, scl, shf, o);
    *(float4*)(&tile[r][q * 4]) = o;
  }
  __syncthreads();

  const int tx = t & 63;   // output column (40 active)
  const int wv = t >> 6;   // wave id: rows wv*8 .. wv*8+7
  const int jj = (tx < OUTD) ? tx : 0;
  const float* __restrict__ wrow = Wt + (size_t)jj * KK;
  float acc[8] = {0.f, 0.f, 0.f, 0.f, 0.f, 0.f, 0.f, 0.f};
#pragma unroll 2
  for (int k = 0; k < F; k += 4) {
    float4 w = *(const float4*)(wrow + k);
#pragma unroll
    for (int r = 0; r < 8; ++r) {
      float4 a = *(const float4*)(&tile[wv * 8 + r][k]);  // wave-uniform broadcast
      acc[r] = fmaf(a.x, w.x, acc[r]);
      acc[r] = fmaf(a.y, w.y, acc[r]);
      acc[r] = fmaf(a.z, w.z, acc[r]);
      acc[r] = fmaf(a.w, w.w, acc[r]);
    }
  }
  __syncthreads();  // done reading agg tile

#pragma unroll
  for (int rr = 0; rr < 4; ++rr) {
    int r = grp * 4 + rr;
    float4 v = *(const float4*)(hin + (size_t)(row0 + r) * F + q * 4);
    bnrelu4(v, scl, shf);
    *(float4*)(&tile[r][q * 4]) = v;
  }
  __syncthreads();

#pragma unroll 2
  for (int k = 0; k < F; k += 4) {
    float4 w = *(const float4*)(wrow + F + k);
#pragma unroll
    for (int r = 0; r < 8; ++r) {
      float4 a = *(const float4*)(&tile[wv * 8 + r][k]);
      acc[r] = fmaf(a.x, w.x, acc[r]);
      acc[r] = fmaf(a.y, w.y, acc[r]);
      acc[r] = fmaf(a.z, w.z, acc[r]);
      acc[r] = fmaf(a.w, w.w, acc[r]);
    }
  }

  float bias = bl[jj];
#pragma unroll
  for (int r = 0; r < 8; ++r) {
    float v = acc[r] + bias;
    float m = (tx < OUTD) ? v : -INFINITY;
#pragma unroll
    for (int off = 32; off > 0; off >>= 1) m = fmaxf(m, __shfl_xor(m, off));
    float e = (tx < OUTD) ? expf(v - m) : 0.f;
    float s = e;
#pragma unroll
    for (int off = 32; off > 0; off >>= 1) s += __shfl_xor(s, off);
    if (tx < OUTD) out[(size_t)(row0 + wv * 8 + r) * OUTD + tx] = v - m - logf(s);
  }
}

// ---------------- driver ----------------
extern "C" void kernel_launch(void* const* d_in, const int* in_sizes, int n_in,
                              void* d_out, int out_size, void* d_ws, size_t ws_size,
                              hipStream_t stream) {
  const float* x = (const float*)d_in[0];
  const int* ei_raw = (const int*)d_in[1];
  const float* Wl[4] = {(const float*)d_in[2], (const float*)d_in[5],
                        (const float*)d_in[8], (const float*)d_in[11]};
  const float* bl[4] = {(const float*)d_in[3], (const float*)d_in[6],
                        (const float*)d_in[9], (const float*)d_in[12]};
  const float* Wr[4] = {(const float*)d_in[4], (const float*)d_in[7],
                        (const float*)d_in[10], (const float*)d_in[13]};
  const float* g[3] = {(const float*)d_in[14], (const float*)d_in[16],
                       (const float*)d_in[18]};
  const float* bb[3] = {(const float*)d_in[15], (const float*)d_in[17],
                        (const float*)d_in[19]};

  char* wsb = (char*)d_ws;
  float* hA  = (float*)wsb;                       wsb += (size_t)NN * F * 4;
  float* hB  = (float*)wsb;                       wsb += (size_t)NN * F * 4;
  int* es    = (int*)wsb;                         wsb += (size_t)2 * NE * 4;
  int* eidx  = (int*)wsb;                         wsb += (size_t)NE * 4;
  int* offs  = (int*)wsb;                         wsb += (size_t)(NN + 64) * 4;
  int* woff  = (int*)wsb;                         wsb += (size_t)(NN + 64) * 4;
  int* bsum  = (int*)wsb;                         wsb += 512 * 4;
  float* sums = (float*)wsb;                      wsb += 256 * 4;
  float* sc   = (float*)wsb;                      wsb += 256 * 4;
  float* Wt   = (float*)wsb;                      wsb += (size_t)OUTD * KK * 4;
  int* flag   = (int*)wsb;                        wsb += 256;

  int* esrc = es;
  int* edst = es + NE;

  // --- edge_index normalization (int64 vs int32) ---
  detect_kernel<<<1, 256, 0, stream>>>(ei_raw, flag);
  conv_kernel<<<(2 * NE + 255) / 256, 256, 0, stream>>>(ei_raw, flag, es);

  // --- CSR build (dst-keyed) + W4 transpose ---
  hipMemsetAsync(woff, 0, NN * sizeof(int), stream);
  deg_kernel<<<NE / 256, 256, 0, stream>>>(edst, woff);
  scan1<<<NB, 256, 0, stream>>>(woff, offs, bsum);
  scan2<<<1, 512, 0, stream>>>(bsum);
  scan3<<<NB, 256, 0, stream>>>(offs, woff, bsum);
  fill_kernel<<<NE / 256, 256, 0, stream>>>(esrc, edst, woff, eidx);
  transpose_w<<<(OUTD * KK + 255) / 256, 256, 0, stream>>>(Wl[3], Wr[3], Wt);

  const float* cur = x;
  float* bufs[2] = {hA, hB};
  for (int L = 0; L < 3; ++L) {
    float* hpre = bufs[L & 1];
    hipMemsetAsync(sums, 0, 256 * sizeof(float), stream);
    if (L == 0)
      fused_layer<0><<<NLB, 256, 0, stream>>>(cur, eidx, offs, nullptr, Wl[L],
                                              bl[L], Wr[L], hpre, sums);
    else
      fused_layer<1><<<NLB, 256, 0, stream>>>(cur, eidx, offs, sc, Wl[L], bl[L],
                                              Wr[L], hpre, sums);
    bn_params<<<1, 128, 0, stream>>>(sums, g[L], bb[L], sc);
    cur = hpre;
  }
  // layer 4 + log_softmax (both BN applications fused in-kernel)
  fused_final<<<NN / 32, 256, 0, stream>>>(cur, eidx, offs, sc, Wt, bl[3],
                                           (float*)d_out);
}

// Round 9
// 815.475 us; speedup vs baseline: 1.5129x; 1.0237x over previous
//
#include <hip/hip_runtime.h>
#include <math.h>

#define NN 100000
#define NE 800000
#define F 128
#define KK 256
#define OUTD 40
#define EPSF 1e-5f
#define NB 391   // ceil(NN/256)
#define LROWS 64 // rows per block in fused_layer
#define NLB 1563 // ceil(NN/64)

// ---------------- edge_index dtype normalization ----------------
__global__ void detect_kernel(const int* __restrict__ ei_raw, int* __restrict__ flag) {
  __shared__ int any;
  if (threadIdx.x == 0) any = 0;
  __syncthreads();
  if (ei_raw[2 * threadIdx.x + 1] != 0) atomicOr(&any, 1);
  __syncthreads();
  if (threadIdx.x == 0) *flag = (any == 0) ? 1 : 0;  // 1 => int64 source
}

__global__ __launch_bounds__(256) void conv_kernel(const int* __restrict__ ei_raw,
                                                   const int* __restrict__ flag,
                                                   int* __restrict__ es) {
  int i = blockIdx.x * 256 + threadIdx.x;
  if (i < 2 * NE) {
    int f = *flag;
    es[i] = f ? ei_raw[2 * i] : ei_raw[i];
  }
}

// ---------------- CSR build (dst-keyed, stores src) ----------------
__global__ __launch_bounds__(256) void deg_kernel(const int* __restrict__ dst,
                                                  int* __restrict__ deg) {
  int e = blockIdx.x * 256 + threadIdx.x;
  if (e < NE) atomicAdd(&deg[dst[e]], 1);
}

__global__ __launch_bounds__(256) void scan1(const int* __restrict__ deg,
                                             int* __restrict__ offs,
                                             int* __restrict__ bsum) {
  __shared__ int sh[256];
  const int tid = threadIdx.x;
  const int i = blockIdx.x * 256 + tid;
  int v = (i < NN) ? deg[i] : 0;
  sh[tid] = v;
  __syncthreads();
#pragma unroll
  for (int off = 1; off < 256; off <<= 1) {
    int add = (tid >= off) ? sh[tid - off] : 0;
    __syncthreads();
    sh[tid] += add;
    __syncthreads();
  }
  if (i < NN) offs[i] = sh[tid] - v;  // exclusive
  if (tid == 255) bsum[blockIdx.x] = sh[255];
}

__global__ void scan2(int* __restrict__ bsum) {
  __shared__ int sh[512];
  const int t = threadIdx.x;
  int v = (t < NB) ? bsum[t] : 0;
  sh[t] = v;
  __syncthreads();
#pragma unroll
  for (int off = 1; off < 512; off <<= 1) {
    int add = (t >= off) ? sh[t - off] : 0;
    __syncthreads();
    sh[t] += add;
    __syncthreads();
  }
  if (t < NB) bsum[t] = sh[t] - v;  // exclusive block offsets
}

__global__ __launch_bounds__(256) void scan3(int* __restrict__ offs,
                                             int* __restrict__ woff,
                                             const int* __restrict__ bsum) {
  int i = blockIdx.x * 256 + threadIdx.x;
  if (i < NN) {
    int o = offs[i] + bsum[blockIdx.x];
    offs[i] = o;
    woff[i] = o;
  }
  if (i == 0) offs[NN] = NE;
}

__global__ __launch_bounds__(256) void fill_kernel(const int* __restrict__ src,
                                                   const int* __restrict__ dst,
                                                   int* __restrict__ woff,
                                                   int* __restrict__ eidx) {
  int e = blockIdx.x * 256 + threadIdx.x;
  if (e < NE) {
    int pos = atomicAdd(&woff[dst[e]], 1);
    eidx[pos] = src[e];
  }
}

// ---------------- W4 transpose: Wt[j][k] over concat-K ----------------
__global__ __launch_bounds__(256) void transpose_w(const float* __restrict__ Wl,
                                                   const float* __restrict__ Wr,
                                                   float* __restrict__ Wt) {
  int i = blockIdx.x * 256 + threadIdx.x;  // OUTD*KK
  if (i < OUTD * KK) {
    int j = i / KK, k = i - j * KK;
    Wt[i] = (k < F) ? Wl[k * OUTD + j] : Wr[(k - F) * OUTD + j];
  }
}

// ---------------- shared helpers ----------------
__device__ __forceinline__ void bnrelu4(float4& v, const float4& s, const float4& b) {
  v.x = fmaxf(fmaf(v.x, s.x, b.x), 0.f);
  v.y = fmaxf(fmaf(v.y, s.y, b.y), 0.f);
  v.z = fmaxf(fmaf(v.z, s.z, b.z), 0.f);
  v.w = fmaxf(fmaf(v.w, s.w, b.w), 0.f);
}

// gather-mean of one row's edge list into (ax..aw), 8-deep ILP.
template <int BN>
__device__ __forceinline__ void gather_row(const float* __restrict__ hin,
                                           const int* __restrict__ eidx,
                                           int beg, int end, int q,
                                           const float4& scl, const float4& shf,
                                           float4& out) {
  float ax = 0.f, ay = 0.f, az = 0.f, aw = 0.f;
#define ACCV(vv)                                       \
  do {                                                 \
    if (BN) bnrelu4(vv, scl, shf);                     \
    ax += vv.x; ay += vv.y; az += vv.z; aw += vv.w;    \
  } while (0)
  int i = beg;
  for (; i + 8 <= end; i += 8) {
    int s0 = eidx[i],     s1 = eidx[i + 1], s2 = eidx[i + 2], s3 = eidx[i + 3];
    int s4 = eidx[i + 4], s5 = eidx[i + 5], s6 = eidx[i + 6], s7 = eidx[i + 7];
    float4 v0 = *(const float4*)(hin + (size_t)s0 * F + q * 4);
    float4 v1 = *(const float4*)(hin + (size_t)s1 * F + q * 4);
    float4 v2 = *(const float4*)(hin + (size_t)s2 * F + q * 4);
    float4 v3 = *(const float4*)(hin + (size_t)s3 * F + q * 4);
    float4 v4 = *(const float4*)(hin + (size_t)s4 * F + q * 4);
    float4 v5 = *(const float4*)(hin + (size_t)s5 * F + q * 4);
    float4 v6 = *(const float4*)(hin + (size_t)s6 * F + q * 4);
    float4 v7 = *(const float4*)(hin + (size_t)s7 * F + q * 4);
    ACCV(v0); ACCV(v1); ACCV(v2); ACCV(v3);
    ACCV(v4); ACCV(v5); ACCV(v6); ACCV(v7);
  }
  for (; i + 2 <= end; i += 2) {
    int s0 = eidx[i], s1 = eidx[i + 1];
    float4 v0 = *(const float4*)(hin + (size_t)s0 * F + q * 4);
    float4 v1 = *(const float4*)(hin + (size_t)s1 * F + q * 4);
    ACCV(v0); ACCV(v1);
  }
  if (i < end) {
    int s0 = eidx[i];
    float4 v0 = *(const float4*)(hin + (size_t)s0 * F + q * 4);
    ACCV(v0);
  }
#undef ACCV
  float m = 1.0f / fmaxf((float)(end - beg), 1.0f);
  out.x = ax * m; out.y = ay * m; out.z = az * m; out.w = aw * m;
}

// one K=128 FMA half over a 64-row tile: acc[8][4] += tile @ Wp
__device__ __forceinline__ void fma_half64(const float (*tile)[F],
                                           const float* __restrict__ Wp,
                                           int tx, int ty, float acc[8][4]) {
  for (int k = 0; k < F; k += 4) {
    float4 in4[8];
#pragma unroll
    for (int r = 0; r < 8; ++r)
      in4[r] = *(const float4*)(&tile[ty * 8 + r][k]);
#pragma unroll
    for (int i = 0; i < 4; ++i) {
      float4 w = *(const float4*)(Wp + (size_t)(k + i) * F + tx * 4);
      float a[8];
#pragma unroll
      for (int r = 0; r < 8; ++r) a[r] = ((const float*)&in4[r])[i];
#pragma unroll
      for (int r = 0; r < 8; ++r) {
        acc[r][0] = fmaf(a[r], w.x, acc[r][0]);
        acc[r][1] = fmaf(a[r], w.y, acc[r][1]);
        acc[r][2] = fmaf(a[r], w.z, acc[r][2]);
        acc[r][3] = fmaf(a[r], w.w, acc[r][3]);
      }
    }
  }
}

// ------ fused layer (64-row tile): gather-mean + dual GEMM + BN-stats --------
// NOTE: NO inter-phase __syncthreads. Each half-wave group (t>>5) writes and
// reads ONLY tile rows 8g..8g+7: all LDS deps are intra-wave64, and DS ops
// complete in order per wave (compiler inserts lgkmcnt). Waves free-run their
// gather->FMA->root->FMA pipeline, keeping gather loads in flight at all times.
template <int BN>
__global__ __launch_bounds__(256) void fused_layer(const float* __restrict__ hin,
                                                   const int* __restrict__ eidx,
                                                   const int* __restrict__ offs,
                                                   const float* __restrict__ sc,
                                                   const float* __restrict__ Wl,
                                                   const float* __restrict__ bl,
                                                   const float* __restrict__ Wr,
                                                   float* __restrict__ out,
                                                   float* __restrict__ sums) {
  __shared__ float tile[LROWS][F];  // 32 KB
  const int t = threadIdx.x;
  const int row0 = blockIdx.x * LROWS;
  const int q = t & 31;
  const int grp = t >> 5;  // 8 groups x 8 rows
  float4 scl, shf;
  if (BN) {
    scl = *(const float4*)(sc + q * 4);
    shf = *(const float4*)(sc + 128 + q * 4);
  }

  // phase A: gather-mean 8 rows (own rows only)
#pragma unroll 1
  for (int rr = 0; rr < 8; ++rr) {
    int r = grp * 8 + rr;
    int n = row0 + r;
    float4 o = {0.f, 0.f, 0.f, 0.f};
    if (n < NN) {
      int beg = offs[n];
      int end = offs[n + 1];
      gather_row<BN>(hin, eidx, beg, end, q, scl, shf, o);
    }
    *(float4*)(&tile[r][q * 4]) = o;
  }
  // no barrier: intra-wave LDS dependency

  const int tx = t & 31;
  const int ty = t >> 5;
  float acc[8][4];
#pragma unroll
  for (int r = 0; r < 8; ++r)
#pragma unroll
    for (int c = 0; c < 4; ++c) acc[r][c] = 0.f;

  fma_half64(tile, Wl, tx, ty, acc);
  // no barrier: this group's reads of its rows precede its own overwrites (in-order DS)

  // phase B: root rows (own rows only)
#pragma unroll
  for (int rr = 0; rr < 8; ++rr) {
    int r = grp * 8 + rr;
    int row = row0 + r;
    float4 v = {0.f, 0.f, 0.f, 0.f};
    if (row < NN) {
      v = *(const float4*)(hin + (size_t)row * F + q * 4);
      if (BN) bnrelu4(v, scl, shf);
    }
    *(float4*)(&tile[r][q * 4]) = v;
  }
  // no barrier: intra-wave

  fma_half64(tile, Wr, tx, ty, acc);

  float4 b4 = *(const float4*)(bl + tx * 4);
  float ps[4] = {0.f, 0.f, 0.f, 0.f};
  float pq[4] = {0.f, 0.f, 0.f, 0.f};
#pragma unroll
  for (int r = 0; r < 8; ++r) {
    int row = row0 + ty * 8 + r;
    if (row < NN) {
      float4 o;
      o.x = acc[r][0] + b4.x;
      o.y = acc[r][1] + b4.y;
      o.z = acc[r][2] + b4.z;
      o.w = acc[r][3] + b4.w;
      ps[0] += o.x; pq[0] = fmaf(o.x, o.x, pq[0]);
      ps[1] += o.y; pq[1] = fmaf(o.y, o.y, pq[1]);
      ps[2] += o.z; pq[2] = fmaf(o.z, o.z, pq[2]);
      ps[3] += o.w; pq[3] = fmaf(o.w, o.w, pq[3]);
      *(float4*)(out + (size_t)row * F + tx * 4) = o;
    }
  }
  // BN-stats epilogue: tile reused as CROSS-WAVE scratch -> barriers required here
  __syncthreads();
  float* red = &tile[0][0];  // [2][8][128] floats = 8 KB
#pragma unroll
  for (int j = 0; j < 4; ++j) {
    red[ty * 128 + tx * 4 + j] = ps[j];
    red[2048 + ty * 128 + tx * 4 + j] = pq[j];
  }
  __syncthreads();
  if (t < 128) {
    float s = 0.f, qq = 0.f;
#pragma unroll
    for (int g2 = 0; g2 < 8; ++g2) {
      s += red[g2 * 128 + t];
      qq += red[2048 + g2 * 128 + t];
    }
    atomicAdd(&sums[t], s);
    atomicAdd(&sums[128 + t], qq);
  }
}

// ---------------- BN parameter computation ----------------
__global__ void bn_params(const float* __restrict__ sums, const float* __restrict__ g,
                          const float* __restrict__ b, float* __restrict__ sc) {
  int c = threadIdx.x;  // 128
  float mu = sums[c] * (1.0f / NN);
  float var = sums[128 + c] * (1.0f / NN) - mu * mu;
  float scale = g[c] * rsqrtf(var + EPSF);
  sc[c] = scale;
  sc[128 + c] = b[c] - mu * scale;
}

// ------ fused final: gather-mean + [K=256 -> 40] GEMM + log_softmax ----------
// Wave wv's tile rows (8wv..8wv+7) are written by its own half-wave groups
// (2wv, 2wv+1) -> all LDS deps intra-wave -> NO barriers at all.
__global__ __launch_bounds__(256) void fused_final(const float* __restrict__ hin,
                                                   const int* __restrict__ eidx,
                                                   const int* __restrict__ offs,
                                                   const float* __restrict__ sc,
                                                   const float* __restrict__ Wt,
                                                   const float* __restrict__ bl,
                                                   float* __restrict__ out) {
  __shared__ float tile[32][F];  // 16 KB
  const int t = threadIdx.x;
  const int row0 = blockIdx.x * 32;
  const int q = t & 31;
  const int grp = t >> 5;
  float4 scl = *(const float4*)(sc + q * 4);
  float4 shf = *(const float4*)(sc + 128 + q * 4);

#pragma unroll 1
  for (int rr = 0; rr < 4; ++rr) {
    int r = grp * 4 + rr;
    int n = row0 + r;
    int beg = offs[n];
    int end = offs[n + 1];
    float4 o;
    gather_row<1>(hin, eidx, beg, end, q, scl, shf, o);
    *(float4*)(&tile[r][q * 4]) = o;
  }
  // no barrier: intra-wave

  const int tx = t & 63;   // output column (40 active)
  const int wv = t >> 6;   // wave id: rows wv*8 .. wv*8+7
  const int jj = (tx < OUTD) ? tx : 0;
  const float* __restrict__ wrow = Wt + (size_t)jj * KK;
  float acc[8] = {0.f, 0.f, 0.f, 0.f, 0.f, 0.f, 0.f, 0.f};
#pragma unroll 2
  for (int k = 0; k < F; k += 4) {
    float4 w = *(const float4*)(wrow + k);
#pragma unroll
    for (int r = 0; r < 8; ++r) {
      float4 a = *(const float4*)(&tile[wv * 8 + r][k]);  // wave-uniform broadcast
      acc[r] = fmaf(a.x, w.x, acc[r]);
      acc[r] = fmaf(a.y, w.y, acc[r]);
      acc[r] = fmaf(a.z, w.z, acc[r]);
      acc[r] = fmaf(a.w, w.w, acc[r]);
    }
  }
  // no barrier: in-order DS, own rows

#pragma unroll
  for (int rr = 0; rr < 4; ++rr) {
    int r = grp * 4 + rr;
    float4 v = *(const float4*)(hin + (size_t)(row0 + r) * F + q * 4);
    bnrelu4(v, scl, shf);
    *(float4*)(&tile[r][q * 4]) = v;
  }
  // no barrier: intra-wave

#pragma unroll 2
  for (int k = 0; k < F; k += 4) {
    float4 w = *(const float4*)(wrow + F + k);
#pragma unroll
    for (int r = 0; r < 8; ++r) {
      float4 a = *(const float4*)(&tile[wv * 8 + r][k]);
      acc[r] = fmaf(a.x, w.x, acc[r]);
      acc[r] = fmaf(a.y, w.y, acc[r]);
      acc[r] = fmaf(a.z, w.z, acc[r]);
      acc[r] = fmaf(a.w, w.w, acc[r]);
    }
  }

  float bias = bl[jj];
#pragma unroll
  for (int r = 0; r < 8; ++r) {
    float v = acc[r] + bias;
    float m = (tx < OUTD) ? v : -INFINITY;
#pragma unroll
    for (int off = 32; off > 0; off >>= 1) m = fmaxf(m, __shfl_xor(m, off));
    float e = (tx < OUTD) ? expf(v - m) : 0.f;
    float s = e;
#pragma unroll
    for (int off = 32; off > 0; off >>= 1) s += __shfl_xor(s, off);
    if (tx < OUTD) out[(size_t)(row0 + wv * 8 + r) * OUTD + tx] = v - m - logf(s);
  }
}

// ---------------- driver ----------------
extern "C" void kernel_launch(void* const* d_in, const int* in_sizes, int n_in,
                              void* d_out, int out_size, void* d_ws, size_t ws_size,
                              hipStream_t stream) {
  const float* x = (const float*)d_in[0];
  const int* ei_raw = (const int*)d_in[1];
  const float* Wl[4] = {(const float*)d_in[2], (const float*)d_in[5],
                        (const float*)d_in[8], (const float*)d_in[11]};
  const float* bl[4] = {(const float*)d_in[3], (const float*)d_in[6],
                        (const float*)d_in[9], (const float*)d_in[12]};
  const float* Wr[4] = {(const float*)d_in[4], (const float*)d_in[7],
                        (const float*)d_in[10], (const float*)d_in[13]};
  const float* g[3] = {(const float*)d_in[14], (const float*)d_in[16],
                       (const float*)d_in[18]};
  const float* bb[3] = {(const float*)d_in[15], (const float*)d_in[17],
                        (const float*)d_in[19]};

  char* wsb = (char*)d_ws;
  float* hA  = (float*)wsb;                       wsb += (size_t)NN * F * 4;
  float* hB  = (float*)wsb;                       wsb += (size_t)NN * F * 4;
  int* es    = (int*)wsb;                         wsb += (size_t)2 * NE * 4;
  int* eidx  = (int*)wsb;                         wsb += (size_t)NE * 4;
  int* offs  = (int*)wsb;                         wsb += (size_t)(NN + 64) * 4;
  int* woff  = (int*)wsb;                         wsb += (size_t)(NN + 64) * 4;
  int* bsum  = (int*)wsb;                         wsb += 512 * 4;
  float* sums = (float*)wsb;                      wsb += 256 * 4;
  float* sc   = (float*)wsb;                      wsb += 256 * 4;
  float* Wt   = (float*)wsb;                      wsb += (size_t)OUTD * KK * 4;
  int* flag   = (int*)wsb;                        wsb += 256;

  int* esrc = es;
  int* edst = es + NE;

  // --- edge_index normalization (int64 vs int32) ---
  detect_kernel<<<1, 256, 0, stream>>>(ei_raw, flag);
  conv_kernel<<<(2 * NE + 255) / 256, 256, 0, stream>>>(ei_raw, flag, es);

  // --- CSR build (dst-keyed) + W4 transpose ---
  hipMemsetAsync(woff, 0, NN * sizeof(int), stream);
  deg_kernel<<<NE / 256, 256, 0, stream>>>(edst, woff);
  scan1<<<NB, 256, 0, stream>>>(woff, offs, bsum);
  scan2<<<1, 512, 0, stream>>>(bsum);
  scan3<<<NB, 256, 0, stream>>>(offs, woff, bsum);
  fill_kernel<<<NE / 256, 256, 0, stream>>>(esrc, edst, woff, eidx);
  transpose_w<<<(OUTD * KK + 255) / 256, 256, 0, stream>>>(Wl[3], Wr[3], Wt);

  const float* cur = x;
  float* bufs[2] = {hA, hB};
  for (int L = 0; L < 3; ++L) {
    float* hpre = bufs[L & 1];
    hipMemsetAsync(sums, 0, 256 * sizeof(float), stream);
    if (L == 0)
      fused_layer<0><<<NLB, 256, 0, stream>>>(cur, eidx, offs, nullptr, Wl[L],
                                              bl[L], Wr[L], hpre, sums);
    else
      fused_layer<1><<<NLB, 256, 0, stream>>>(cur, eidx, offs, sc, Wl[L], bl[L],
                                              Wr[L], hpre, sums);
    bn_params<<<1, 128, 0, stream>>>(sums, g[L], bb[L], sc);
    cur = hpre;
  }
  // layer 4 + log_softmax (both BN applications fused in-kernel)
  fused_final<<<NN / 32, 256, 0, stream>>>(cur, eidx, offs, sc, Wt, bl[3],
                                           (float*)d_out);
}